// Round 1
// baseline (661.064 us; speedup 1.0000x reference)
//
#include <hip/hip_runtime.h>
#include <math.h>

#define NB 32
#define NH 256
#define NLC 1024
#define NLQ 256
#define NEGV (-1e30f)

// Inner product micro-kernel: 16 K-steps, 4x4 per thread.
#define INNER16(AS, BS)                                                        \
  _Pragma("unroll")                                                            \
  for (int k = 0; k < 16; ++k) {                                               \
    float4 a4 = *(const float4*)&AS[k][ty << 2];                               \
    float4 b4 = *(const float4*)&BS[k][tx << 2];                               \
    float a_[4] = {a4.x, a4.y, a4.z, a4.w};                                    \
    float b_[4] = {b4.x, b4.y, b4.z, b4.w};                                    \
    _Pragma("unroll")                                                          \
    for (int i = 0; i < 4; ++i)                                                \
      _Pragma("unroll")                                                        \
      for (int j = 0; j < 4; ++j) acc[i][j] += a_[i] * b_[j];                  \
  }

// s1[b][l] = sum_h C[b][h][l] * w1[h]
__global__ __launch_bounds__(256) void k_s1(const float* __restrict__ C,
                                            const float* __restrict__ w,
                                            float* __restrict__ s1) {
  int b = blockIdx.x >> 2;  // LC/256 = 4 blocks per batch
  int l = ((blockIdx.x & 3) << 8) + threadIdx.x;
  const float* Cb = C + (size_t)b * NH * NLC;
  float acc = 0.f;
#pragma unroll 8
  for (int h = 0; h < NH; ++h) acc += Cb[(size_t)h * NLC + l] * w[h];
  s1[b * NLC + l] = acc;
}

// s2[b][m] = sum_h Q[b][h][m] * w2[h]
__global__ __launch_bounds__(256) void k_s2(const float* __restrict__ Q,
                                            const float* __restrict__ w,
                                            float* __restrict__ s2) {
  int b = blockIdx.x;
  int m = threadIdx.x;
  const float* Qb = Q + (size_t)b * NH * NLQ;
  const float* w2 = w + NH;
  float acc = 0.f;
#pragma unroll 8
  for (int h = 0; h < NH; ++h) acc += Qb[(size_t)h * NLQ + m] * w2[h];
  s2[b * NLQ + m] = acc;
}

// S[b][l][m] = s1[l] + s2[m] + sum_h (C[b][h][l]*w3[h]) * Q[b][h][m]
__global__ __launch_bounds__(256) void k_sgemm(
    const float* __restrict__ C, const float* __restrict__ Q,
    const float* __restrict__ w, const float* __restrict__ s1,
    const float* __restrict__ s2, float* __restrict__ S) {
  __shared__ float As[16][64];
  __shared__ float Bs[16][64];
  int b = blockIdx.z;
  int l0 = blockIdx.y << 6;
  int m0 = blockIdx.x << 6;
  const float* Cb = C + (size_t)b * NH * NLC;
  const float* Qb = Q + (size_t)b * NH * NLQ;
  const float* w3 = w + 2 * NH;
  int t = threadIdx.x;
  int tx = t & 15, ty = t >> 4;
  int kk = t >> 4, c4 = (t & 15) << 2;
  float acc[4][4] = {};
  for (int k0 = 0; k0 < NH; k0 += 16) {
    float w3v = w3[k0 + kk];
    float4 av = *(const float4*)&Cb[(size_t)(k0 + kk) * NLC + l0 + c4];
    float4 bv = *(const float4*)&Qb[(size_t)(k0 + kk) * NLQ + m0 + c4];
    __syncthreads();
    *(float4*)&As[kk][c4] =
        make_float4(av.x * w3v, av.y * w3v, av.z * w3v, av.w * w3v);
    *(float4*)&Bs[kk][c4] = bv;
    __syncthreads();
    INNER16(As, Bs)
  }
  int l = l0 + (ty << 2);
  int m = m0 + (tx << 2);
  float4 s2v = *(const float4*)&s2[b * NLQ + m];
  float s2a[4] = {s2v.x, s2v.y, s2v.z, s2v.w};
#pragma unroll
  for (int i = 0; i < 4; ++i) {
    float s1v = s1[b * NLC + l + i];
    float4 o = make_float4(acc[i][0] + s1v + s2a[0], acc[i][1] + s1v + s2a[1],
                           acc[i][2] + s1v + s2a[2], acc[i][3] + s1v + s2a[3]);
    *(float4*)&S[((size_t)b * NLC + l + i) * NLQ + m] = o;
  }
}

// per-row (over m) masked max & sum-exp. One wave per row.
__global__ __launch_bounds__(256) void k_rowstats(const float* __restrict__ S,
                                                  const int* __restrict__ qmask,
                                                  float* __restrict__ rmax,
                                                  float* __restrict__ rsum) {
  int wave = threadIdx.x >> 6, lane = threadIdx.x & 63;
  int idx = (blockIdx.x << 2) + wave;  // [0, NB*NLC)
  int b = idx >> 10;
  const float* row = S + (size_t)idx * NLQ;
  const int* qm = qmask + b * NLQ;
  float v[4], mx = -INFINITY;
#pragma unroll
  for (int i = 0; i < 4; ++i) {
    int m = lane + (i << 6);
    float x = row[m] + (qm[m] ? 0.f : NEGV);
    v[i] = x;
    mx = fmaxf(mx, x);
  }
#pragma unroll
  for (int off = 32; off > 0; off >>= 1) mx = fmaxf(mx, __shfl_xor(mx, off));
  float sm = 0.f;
#pragma unroll
  for (int i = 0; i < 4; ++i) sm += expf(v[i] - mx);
#pragma unroll
  for (int off = 32; off > 0; off >>= 1) sm += __shfl_xor(sm, off);
  if (lane == 0) {
    rmax[idx] = mx;
    rsum[idx] = sm;
  }
}

// per-column (over l) masked max & sum-exp, online. 64 columns per block.
__global__ __launch_bounds__(256) void k_colstats(const float* __restrict__ S,
                                                  const int* __restrict__ cmask,
                                                  float* __restrict__ cmax,
                                                  float* __restrict__ csum) {
  int b = blockIdx.x >> 2;  // LQ/64 = 4
  int m0 = (blockIdx.x & 3) << 6;
  int tx = threadIdx.x & 63, ty = threadIdx.x >> 6;
  const float* Sb = S + (size_t)b * NLC * NLQ;
  const int* cm = cmask + b * NLC;
  float mx = -INFINITY, sm = 0.f;
  for (int l = ty; l < NLC; l += 4) {
    float x = Sb[(size_t)l * NLQ + m0 + tx] + (cm[l] ? 0.f : NEGV);
    float nmx = fmaxf(mx, x);
    sm = sm * expf(mx - nmx) + expf(x - nmx);
    mx = nmx;
  }
  __shared__ float smx[4][64], ssm[4][64];
  smx[ty][tx] = mx;
  ssm[ty][tx] = sm;
  __syncthreads();
  if (ty == 0) {
#pragma unroll
    for (int r = 1; r < 4; ++r) {
      float m2 = smx[r][tx], s2 = ssm[r][tx];
      float nm = fmaxf(mx, m2);
      sm = sm * expf(mx - nm) + s2 * expf(m2 - nm);
      mx = nm;
    }
    cmax[b * NLQ + m0 + tx] = mx;
    csum[b * NLQ + m0 + tx] = sm;
  }
}

// T[b][m][h] = sum_l S_col[l][m] * Ct[l][h];  S_col computed on the fly.
__global__ __launch_bounds__(256) void k_tgemm(
    const float* __restrict__ S, const float* __restrict__ C,
    const int* __restrict__ cmask, const float* __restrict__ cmax,
    const float* __restrict__ csum, float* __restrict__ T) {
  __shared__ float As[16][64];  // As[k(l)][m] = exp(S + negc - cmax[m])
  __shared__ float Bs[16][68];  // Bs[k(l)][h] = Ct[l][h]  (transpose-load from C)
  __shared__ float cmx[64];
  int b = blockIdx.z;
  int m0 = blockIdx.y << 6;
  int h0 = blockIdx.x << 6;
  int t = threadIdx.x;
  if (t < 64) cmx[t] = cmax[b * NLQ + m0 + t];
  int tx = t & 15, ty = t >> 4;
  int kk = t >> 4, c4 = (t & 15) << 2;   // As loader
  int hrow = t >> 2, k4 = (t & 3) << 2;  // Bs loader
  const float* Sb = S + (size_t)b * NLC * NLQ;
  const float* Cb = C + (size_t)b * NH * NLC;
  const int* cm = cmask + b * NLC;
  float acc[4][4] = {};
  __syncthreads();
  for (int k0 = 0; k0 < NLC; k0 += 16) {
    float negc = cm[k0 + kk] ? 0.f : NEGV;
    float4 sv = *(const float4*)&Sb[(size_t)(k0 + kk) * NLQ + m0 + c4];
    float4 cv = *(const float4*)&Cb[(size_t)(h0 + hrow) * NLC + k0 + k4];
    __syncthreads();
    *(float4*)&As[kk][c4] = make_float4(
        expf(sv.x + negc - cmx[c4 + 0]), expf(sv.y + negc - cmx[c4 + 1]),
        expf(sv.z + negc - cmx[c4 + 2]), expf(sv.w + negc - cmx[c4 + 3]));
    Bs[k4 + 0][hrow] = cv.x;
    Bs[k4 + 1][hrow] = cv.y;
    Bs[k4 + 2][hrow] = cv.z;
    Bs[k4 + 3][hrow] = cv.w;
    __syncthreads();
    INNER16(As, Bs)
  }
#pragma unroll
  for (int i = 0; i < 4; ++i) {
    int m = m0 + (ty << 2) + i;
    float inv = 1.f / csum[b * NLQ + m];
    float4 o = make_float4(acc[i][0] * inv, acc[i][1] * inv, acc[i][2] * inv,
                           acc[i][3] * inv);
    *(float4*)&T[((size_t)b * NLQ + m) * NH + h0 + (tx << 2)] = o;
  }
}

// [A | Bv](l, h) = sum_m S_row[l][m] * [Qt | T](m, h); stored TRANSPOSED:
// At[b][h][l], Bvt[b][h][l].
__global__ __launch_bounds__(256) void k_abgemm(
    const float* __restrict__ S, const float* __restrict__ Q,
    const float* __restrict__ T, const int* __restrict__ qmask,
    const float* __restrict__ rmax, const float* __restrict__ rsum,
    float* __restrict__ At, float* __restrict__ Bvt) {
  __shared__ float As[16][68];  // As[k(m)][l] = exp(S + negq - rmax[l])
  __shared__ float Bs[16][68];  // Bs[k(m)][h]
  int b = blockIdx.z;
  int l0 = blockIdx.y << 6;
  int hb = blockIdx.x;
  bool fromQ = hb < 4;
  int h0 = fromQ ? (hb << 6) : ((hb - 4) << 6);
  int t = threadIdx.x;
  int tx = t & 15, ty = t >> 4;
  int row = t >> 2, k4 = (t & 3) << 2;  // transpose loaders
  int kk = t >> 4, c4 = (t & 15) << 2;  // direct loader (T)
  const float* Sb = S + (size_t)b * NLC * NLQ;
  const int* qm = qmask + b * NLQ;
  float rmx = rmax[b * NLC + l0 + row];
  float acc[4][4] = {};
  for (int k0 = 0; k0 < NLQ; k0 += 16) {
    float4 sv = *(const float4*)&Sb[(size_t)(l0 + row) * NLQ + k0 + k4];
    float nq[4];
#pragma unroll
    for (int j = 0; j < 4; ++j) nq[j] = qm[k0 + k4 + j] ? 0.f : NEGV;
    float4 bvv;
    if (fromQ)
      bvv = *(const float4*)&Q[((size_t)b * NH + h0 + row) * NLQ + k0 + k4];
    else
      bvv = *(const float4*)&T[((size_t)b * NLQ + k0 + kk) * NH + h0 + c4];
    __syncthreads();
    As[k4 + 0][row] = expf(sv.x + nq[0] - rmx);
    As[k4 + 1][row] = expf(sv.y + nq[1] - rmx);
    As[k4 + 2][row] = expf(sv.z + nq[2] - rmx);
    As[k4 + 3][row] = expf(sv.w + nq[3] - rmx);
    if (fromQ) {
      Bs[k4 + 0][row] = bvv.x;
      Bs[k4 + 1][row] = bvv.y;
      Bs[k4 + 2][row] = bvv.z;
      Bs[k4 + 3][row] = bvv.w;
    } else {
      *(float4*)&Bs[kk][c4] = bvv;
    }
    __syncthreads();
    INNER16(As, Bs)
  }
  float inv[4];
#pragma unroll
  for (int i = 0; i < 4; ++i)
    inv[i] = 1.f / rsum[b * NLC + l0 + (ty << 2) + i];
  float* dst = fromQ ? At : Bvt;
#pragma unroll
  for (int j = 0; j < 4; ++j) {
    int h = h0 + (tx << 2) + j;
    float4 o = make_float4(acc[0][j] * inv[0], acc[1][j] * inv[1],
                           acc[2][j] * inv[2], acc[3][j] * inv[3]);
    *(float4*)&dst[((size_t)b * NH + h) * NLC + l0 + (ty << 2)] = o;
  }
}

// out[b][h][l] = relu(b_res[h] + sum_f cat[l][f] * W_res[h][f])
// cat regions along f: [Ct | A | Ct*A | Ct*Bv]; all K-major sources.
__global__ __launch_bounds__(256) void k_out(
    const float* __restrict__ C, const float* __restrict__ At,
    const float* __restrict__ Bvt, const float* __restrict__ W,
    const float* __restrict__ br, float* __restrict__ out) {
  __shared__ float As[16][68];  // As[k(f)][h] = W_res[h][f]  (transpose-load)
  __shared__ float Bs[16][64];  // Bs[k(f)][l] = cat[l][f]    (direct, K-major)
  int b = blockIdx.z;
  int h0 = blockIdx.y << 6;
  int l0 = blockIdx.x << 6;
  int t = threadIdx.x;
  int tx = t & 15, ty = t >> 4;
  int kk = t >> 4, c4 = (t & 15) << 2;
  int wrow = t >> 2, k4 = (t & 3) << 2;
  float acc[4][4] = {};
  for (int k0 = 0; k0 < 4 * NH; k0 += 16) {
    int reg = k0 >> 8;
    int hh = (k0 & 255) + kk;
    size_t rowoff = ((size_t)b * NH + hh) * NLC + l0 + c4;
    float4 v;
    if (reg == 0)
      v = *(const float4*)&C[rowoff];
    else if (reg == 1)
      v = *(const float4*)&At[rowoff];
    else {
      float4 cv = *(const float4*)&C[rowoff];
      float4 av = (reg == 2) ? *(const float4*)&At[rowoff]
                             : *(const float4*)&Bvt[rowoff];
      v = make_float4(cv.x * av.x, cv.y * av.y, cv.z * av.z, cv.w * av.w);
    }
    float4 wv = *(const float4*)&W[(size_t)(h0 + wrow) * (4 * NH) + k0 + k4];
    __syncthreads();
    *(float4*)&Bs[kk][c4] = v;
    As[k4 + 0][wrow] = wv.x;
    As[k4 + 1][wrow] = wv.y;
    As[k4 + 2][wrow] = wv.z;
    As[k4 + 3][wrow] = wv.w;
    __syncthreads();
    INNER16(As, Bs)
  }
#pragma unroll
  for (int i = 0; i < 4; ++i) {
    int h = h0 + (ty << 2) + i;
    float bias = br[h];
    float4 o = make_float4(fmaxf(acc[i][0] + bias, 0.f),
                           fmaxf(acc[i][1] + bias, 0.f),
                           fmaxf(acc[i][2] + bias, 0.f),
                           fmaxf(acc[i][3] + bias, 0.f));
    *(float4*)&out[((size_t)b * NH + h) * NLC + l0 + (tx << 2)] = o;
  }
}

extern "C" void kernel_launch(void* const* d_in, const int* in_sizes, int n_in,
                              void* d_out, int out_size, void* d_ws,
                              size_t ws_size, hipStream_t stream) {
  (void)in_sizes;
  (void)n_in;
  (void)out_size;
  (void)ws_size;
  const float* C = (const float*)d_in[0];
  const float* Q = (const float*)d_in[1];
  const int* cmask = (const int*)d_in[2];
  const int* qmask = (const int*)d_in[3];
  const float* w = (const float*)d_in[4];
  const float* W = (const float*)d_in[5];
  const float* br = (const float*)d_in[6];
  float* out = (float*)d_out;

  float* ws = (float*)d_ws;
  float* S = ws;                              // NB*NLC*NLQ  = 8388608
  float* At = S + (size_t)NB * NLC * NLQ;     // NB*NH*NLC   = 8388608
  float* Bvt = At + (size_t)NB * NH * NLC;    // NB*NH*NLC   = 8388608
  float* T = Bvt + (size_t)NB * NH * NLC;     // NB*NLQ*NH   = 2097152
  float* s1 = T + (size_t)NB * NLQ * NH;      // NB*NLC
  float* s2 = s1 + NB * NLC;                  // NB*NLQ
  float* rmax = s2 + NB * NLQ;                // NB*NLC
  float* rsum = rmax + NB * NLC;              // NB*NLC
  float* cmax = rsum + NB * NLC;              // NB*NLQ
  float* csum = cmax + NB * NLQ;              // NB*NLQ

  k_s1<<<dim3(NB * (NLC / 256)), dim3(256), 0, stream>>>(C, w, s1);
  k_s2<<<dim3(NB), dim3(256), 0, stream>>>(Q, w, s2);
  k_sgemm<<<dim3(NLQ / 64, NLC / 64, NB), dim3(256), 0, stream>>>(C, Q, w, s1,
                                                                  s2, S);
  k_rowstats<<<dim3(NB * NLC / 4), dim3(256), 0, stream>>>(S, qmask, rmax,
                                                           rsum);
  k_colstats<<<dim3(NB * (NLQ / 64)), dim3(256), 0, stream>>>(S, cmask, cmax,
                                                              csum);
  k_tgemm<<<dim3(NH / 64, NLQ / 64, NB), dim3(256), 0, stream>>>(S, C, cmask,
                                                                 cmax, csum, T);
  k_abgemm<<<dim3(2 * NH / 64, NLC / 64, NB), dim3(256), 0, stream>>>(
      S, Q, T, qmask, rmax, rsum, At, Bvt);
  k_out<<<dim3(NLC / 64, NH / 64, NB), dim3(256), 0, stream>>>(C, At, Bvt, W,
                                                               br, out);
}

// Round 2
// 295.055 us; speedup vs baseline: 2.2405x; 2.2405x over previous
//
#include <hip/hip_runtime.h>
#include <math.h>

#define NB 32
#define NH 256
#define NLC 1024
#define NLQ 256
#define NEGV (-1e30f)

typedef short short8 __attribute__((ext_vector_type(8)));
typedef float f32x4 __attribute__((ext_vector_type(4)));

__device__ inline short bf16_of(float f) {
  union { float f; unsigned u; } v;
  v.f = f;
  unsigned r = (v.u + 0x7fffu + ((v.u >> 16) & 1u)) >> 16;
  return (short)r;
}
__device__ inline float f_of(short s) {
  union { unsigned u; float f; } v;
  v.u = ((unsigned)(unsigned short)s) << 16;
  return v.f;
}
__device__ inline short8 cvt8(float4 a, float4 b) {
  short8 o;
  o[0] = bf16_of(a.x); o[1] = bf16_of(a.y); o[2] = bf16_of(a.z); o[3] = bf16_of(a.w);
  o[4] = bf16_of(b.x); o[5] = bf16_of(b.y); o[6] = bf16_of(b.z); o[7] = bf16_of(b.w);
  return o;
}

// ---- swizzled 128x32 bf16 LDS tile helpers (row = 64B, slot ^= (row>>1)&3) ----
__device__ inline void lds_w8(short* lds, int r, int c, short8 v) {
  int byteoff = (r << 6) + (((c ^ ((r >> 1) & 3)) & 3) << 4);
  *(short8*)((char*)lds + byteoff) = v;
}
__device__ inline short8 lds_r8(const short* lds, int R, int g) {
  int byteoff = (R << 6) + (((g ^ ((R >> 1) & 3)) & 3) << 4);
  return *(const short8*)((const char*)lds + byteoff);
}
// global_load_lds staging of a 128x32 bf16 tile from K-minor src (ld elements).
// Source pre-permuted so linear LDS bytes match the swizzled-read layout.
__device__ inline void stage_g(const short* src, int ld, short* lds, int t) {
  int L = t & 63, w = t >> 6;
  int cp = (L & 3) ^ ((L >> 3) & 3);
#pragma unroll
  for (int i = 0; i < 2; ++i) {
    int seg = w + i * 4;
    const short* g = src + (size_t)(seg * 16 + (L >> 2)) * ld + cp * 8;
    __builtin_amdgcn_global_load_lds(
        (const __attribute__((address_space(1))) unsigned int*)g,
        (__attribute__((address_space(3))) unsigned int*)(lds + seg * 512), 16,
        0, 0);
  }
}

#define GEMM_IDS                                       \
  int t = threadIdx.x, lane = t & 63, w = t >> 6;      \
  int ln = lane & 15, g = lane >> 4;                   \
  int wr = (w >> 1) << 6, wc = (w & 1) << 6;           \
  (void)wr; (void)wc;

#define MFMA_STEP(AS, BS)                                                      \
  {                                                                            \
    short8 af[4], bfr[4];                                                      \
    _Pragma("unroll") for (int mi = 0; mi < 4; ++mi) af[mi] =                  \
        lds_r8(AS, wr + mi * 16 + ln, g);                                      \
    _Pragma("unroll") for (int ni = 0; ni < 4; ++ni) bfr[ni] =                 \
        lds_r8(BS, wc + ni * 16 + ln, g);                                      \
    _Pragma("unroll") for (int mi = 0; mi < 4; ++mi)                           \
        _Pragma("unroll") for (int ni = 0; ni < 4; ++ni) acc[mi][ni] =         \
            __builtin_amdgcn_mfma_f32_16x16x32_bf16(af[mi], bfr[ni],           \
                                                    acc[mi][ni], 0, 0, 0);     \
  }

// ---------------- prep: Ct_lh[l][h] = bf16(C[h][l]) ----------------
__global__ __launch_bounds__(256) void k_prep_c(const float* __restrict__ C,
                                                short* __restrict__ Ct_lh) {
  __shared__ float Ts[64][65];
  int b = blockIdx.z, h0 = blockIdx.y << 6, l0 = blockIdx.x << 6;
  int t = threadIdx.x;
  int hr = t >> 4, lc = (t & 15) << 2;
  const float* Cb = C + ((size_t)b * NH + h0) * NLC + l0;
#pragma unroll
  for (int i = 0; i < 4; ++i) {
    float4 v = *(const float4*)&Cb[(size_t)(hr + i * 16) * NLC + lc];
    Ts[hr + i * 16][lc + 0] = v.x;
    Ts[hr + i * 16][lc + 1] = v.y;
    Ts[hr + i * 16][lc + 2] = v.z;
    Ts[hr + i * 16][lc + 3] = v.w;
  }
  __syncthreads();
  int lr = t >> 2, hc = (t & 3) << 4;
  short* dst = &Ct_lh[((size_t)b * NLC + l0 + lr) * NH + h0 + hc];
  short8 o0, o1;
#pragma unroll
  for (int j = 0; j < 8; ++j) o0[j] = bf16_of(Ts[hc + j][lr]);
#pragma unroll
  for (int j = 0; j < 8; ++j) o1[j] = bf16_of(Ts[hc + 8 + j][lr]);
  *(short8*)dst = o0;
  *(short8*)(dst + 8) = o1;
}

// ---------------- prep: Qtw3[m][h] = bf16(Q[h][m]*w3[h]) ----------------
__global__ __launch_bounds__(256) void k_prep_q(const float* __restrict__ Q,
                                                const float* __restrict__ w,
                                                short* __restrict__ Qtw3) {
  __shared__ float Ts[64][65];
  int b = blockIdx.z, h0 = blockIdx.y << 6, m0 = blockIdx.x << 6;
  int t = threadIdx.x;
  int hr = t >> 4, mc = (t & 15) << 2;
  const float* w3 = w + 2 * NH;
  const float* Qb = Q + ((size_t)b * NH + h0) * NLQ + m0;
#pragma unroll
  for (int i = 0; i < 4; ++i) {
    int h = hr + i * 16;
    float w3v = w3[h0 + h];
    float4 v = *(const float4*)&Qb[(size_t)h * NLQ + mc];
    Ts[h][mc + 0] = v.x * w3v;
    Ts[h][mc + 1] = v.y * w3v;
    Ts[h][mc + 2] = v.z * w3v;
    Ts[h][mc + 3] = v.w * w3v;
  }
  __syncthreads();
  int mr = t >> 2, hc = (t & 3) << 4;
  short* dst = &Qtw3[((size_t)b * NLQ + m0 + mr) * NH + h0 + hc];
  short8 o0, o1;
#pragma unroll
  for (int j = 0; j < 8; ++j) o0[j] = bf16_of(Ts[hc + j][mr]);
#pragma unroll
  for (int j = 0; j < 8; ++j) o1[j] = bf16_of(Ts[hc + 8 + j][mr]);
  *(short8*)dst = o0;
  *(short8*)(dst + 8) = o1;
}

// s1[b][l] = sum_h C[b][h][l] * w1[h]
__global__ __launch_bounds__(256) void k_s1(const float* __restrict__ C,
                                            const float* __restrict__ w,
                                            float* __restrict__ s1) {
  int b = blockIdx.x >> 2;
  int l = ((blockIdx.x & 3) << 8) + threadIdx.x;
  const float* Cb = C + (size_t)b * NH * NLC;
  float acc = 0.f;
#pragma unroll 8
  for (int h = 0; h < NH; ++h) acc += Cb[(size_t)h * NLC + l] * w[h];
  s1[b * NLC + l] = acc;
}

// s2[b][m] = sum_h Q[b][h][m] * w2[h]
__global__ __launch_bounds__(256) void k_s2(const float* __restrict__ Q,
                                            const float* __restrict__ w,
                                            float* __restrict__ s2) {
  int b = blockIdx.x;
  int m = threadIdx.x;
  const float* Qb = Q + (size_t)b * NH * NLQ;
  const float* w2 = w + NH;
  float acc = 0.f;
#pragma unroll 8
  for (int h = 0; h < NH; ++h) acc += Qb[(size_t)h * NLQ + m] * w2[h];
  s2[b * NLQ + m] = acc;
}

// ---------------- S = Ct_lh @ Qtw3^T + s1 + s2  (M=l, N=m, K=h) ----------------
__global__ __launch_bounds__(256) void k_sgemm(
    const short* __restrict__ Ct_lh, const short* __restrict__ Qtw3,
    const float* __restrict__ s1, const float* __restrict__ s2,
    float* __restrict__ S) {
  __shared__ short As[4096], Bs[4096];
  int b = blockIdx.z, l0 = blockIdx.y << 7, m0 = blockIdx.x << 7;
  GEMM_IDS
  const short* Ag = Ct_lh + ((size_t)b * NLC + l0) * NH;
  const short* Bg = Qtw3 + ((size_t)b * NLQ + m0) * NH;
  f32x4 acc[4][4] = {};
  for (int k0 = 0; k0 < NH; k0 += 32) {
    __syncthreads();
    stage_g(Ag + k0, NH, As, t);
    stage_g(Bg + k0, NH, Bs, t);
    __syncthreads();
    MFMA_STEP(As, Bs)
  }
#pragma unroll
  for (int mi = 0; mi < 4; ++mi)
#pragma unroll
    for (int ni = 0; ni < 4; ++ni)
#pragma unroll
      for (int r = 0; r < 4; ++r) {
        int l = l0 + wr + mi * 16 + g * 4 + r;
        int m = m0 + wc + ni * 16 + ln;
        S[((size_t)b * NLC + l) * NLQ + m] =
            acc[mi][ni][r] + s1[b * NLC + l] + s2[b * NLQ + m];
      }
}

// per-row (over m) masked max & inverse-sum-exp. One wave per row.
__global__ __launch_bounds__(256) void k_rowstats(const float* __restrict__ S,
                                                  const int* __restrict__ qmask,
                                                  float* __restrict__ rmax,
                                                  float* __restrict__ rinv) {
  int wave = threadIdx.x >> 6, lane = threadIdx.x & 63;
  int idx = (blockIdx.x << 2) + wave;
  int b = idx >> 10;
  const float* row = S + (size_t)idx * NLQ;
  const int* qm = qmask + b * NLQ;
  float v[4], mx = -INFINITY;
#pragma unroll
  for (int i = 0; i < 4; ++i) {
    int m = lane + (i << 6);
    float x = row[m] + (qm[m] ? 0.f : NEGV);
    v[i] = x;
    mx = fmaxf(mx, x);
  }
#pragma unroll
  for (int off = 32; off > 0; off >>= 1) mx = fmaxf(mx, __shfl_xor(mx, off));
  float sm = 0.f;
#pragma unroll
  for (int i = 0; i < 4; ++i) sm += expf(v[i] - mx);
#pragma unroll
  for (int off = 32; off > 0; off >>= 1) sm += __shfl_xor(sm, off);
  if (lane == 0) {
    rmax[idx] = mx;
    rinv[idx] = 1.0f / sm;
  }
}

// per-column (over l) masked max & inverse-sum-exp, online.
__global__ __launch_bounds__(256) void k_colstats(const float* __restrict__ S,
                                                  const int* __restrict__ cmask,
                                                  float* __restrict__ cmax,
                                                  float* __restrict__ cinv) {
  int b = blockIdx.x >> 2;
  int m0 = (blockIdx.x & 3) << 6;
  int tx = threadIdx.x & 63, ty = threadIdx.x >> 6;
  const float* Sb = S + (size_t)b * NLC * NLQ;
  const int* cm = cmask + b * NLC;
  float mx = -INFINITY, sm = 0.f;
  for (int l = ty; l < NLC; l += 4) {
    float x = Sb[(size_t)l * NLQ + m0 + tx] + (cm[l] ? 0.f : NEGV);
    float nmx = fmaxf(mx, x);
    sm = sm * expf(mx - nmx) + expf(x - nmx);
    mx = nmx;
  }
  __shared__ float smx[4][64], ssm[4][64];
  smx[ty][tx] = mx;
  ssm[ty][tx] = sm;
  __syncthreads();
  if (ty == 0) {
#pragma unroll
    for (int r = 1; r < 4; ++r) {
      float m2 = smx[r][tx], s2 = ssm[r][tx];
      float nm = fmaxf(mx, m2);
      sm = sm * expf(mx - nm) + s2 * expf(m2 - nm);
      mx = nm;
    }
    cmax[b * NLQ + m0 + tx] = mx;
    cinv[b * NLQ + m0 + tx] = 1.0f / sm;
  }
}

// ---------------- Tt[h][m] = sum_l C[h][l] * S_col[l][m]  (M=h, N=m, K=l) -----
__global__ __launch_bounds__(256) void k_tgemm(
    const float* __restrict__ C, const float* __restrict__ S,
    const int* __restrict__ cmask, const float* __restrict__ cmax,
    const float* __restrict__ cinv, short* __restrict__ Tt) {
  __shared__ short As[4096], Bs[4096];
  int b = blockIdx.z, h0 = blockIdx.y << 7, m0 = blockIdx.x << 7;
  GEMM_IDS
  const float* Cb = C + ((size_t)b * NH + h0) * NLC;
  const float* Sb = S + (size_t)b * NLC * NLQ;
  const float* cmx = cmax + b * NLQ + m0;
  const float* civ = cinv + b * NLQ + m0;
  const int* cm = cmask + b * NLC;
  f32x4 acc[4][4] = {};
  for (int k0 = 0; k0 < NLC; k0 += 32) {
    __syncthreads();
    {  // A: reg-convert from f32 C (rows h, K=l minor)
      int c = lane & 3;
#pragma unroll
      for (int i = 0; i < 2; ++i) {
        int seg = w + i * 4, r = seg * 16 + (lane >> 2);
        const float* src = &Cb[(size_t)r * NLC + k0 + c * 8];
        float4 v0 = *(const float4*)src;
        float4 v1 = *(const float4*)(src + 4);
        lds_w8(As, r, c, cvt8(v0, v1));
      }
    }
    {  // B: transposing exp-staging from f32 S (rows m, K=l)
      int lloc = t >> 3, l = k0 + lloc;
      float cmf = (float)cm[l];
      const float* srow = &Sb[(size_t)l * NLQ + m0];
      int g2 = lloc >> 3, kin = lloc & 7;
#pragma unroll
      for (int mi4 = 0; mi4 < 4; ++mi4) {
        int m = ((t & 7) << 2) + (mi4 << 5);
        float4 sv = *(const float4*)&srow[m];
        float p[4];
        p[0] = expf(sv.x - cmx[m + 0]) * civ[m + 0] * cmf;
        p[1] = expf(sv.y - cmx[m + 1]) * civ[m + 1] * cmf;
        p[2] = expf(sv.z - cmx[m + 2]) * civ[m + 2] * cmf;
        p[3] = expf(sv.w - cmx[m + 3]) * civ[m + 3] * cmf;
#pragma unroll
        for (int j = 0; j < 4; ++j) {
          int R = m + j;
          int byteoff =
              (R << 6) + (((g2 ^ ((R >> 1) & 3)) & 3) << 4) + (kin << 1);
          *(short*)((char*)Bs + byteoff) = bf16_of(p[j]);
        }
      }
    }
    __syncthreads();
    MFMA_STEP(As, Bs)
  }
#pragma unroll
  for (int mi = 0; mi < 4; ++mi)
#pragma unroll
    for (int ni = 0; ni < 4; ++ni)
#pragma unroll
      for (int r = 0; r < 4; ++r) {
        int h = h0 + wr + mi * 16 + g * 4 + r;
        int m = m0 + wc + ni * 16 + ln;
        Tt[((size_t)b * NH + h) * NLQ + m] = bf16_of(acc[mi][ni][r]);
      }
}

// -------- [A|Bv][l][h] = sum_m S_row[l][m] * X[h][m]  (M=l, N=h', K=m) --------
__global__ __launch_bounds__(256) void k_abgemm(
    const float* __restrict__ S, const float* __restrict__ Q,
    const short* __restrict__ Tt, const int* __restrict__ qmask,
    const float* __restrict__ rmax, const float* __restrict__ rinv,
    short* __restrict__ A_lh, short* __restrict__ Bv_lh) {
  __shared__ short As[4096], Bs[4096];
  int b = blockIdx.z, l0 = blockIdx.y << 7, nb = blockIdx.x;
  GEMM_IDS
  const float* Sb = S + ((size_t)b * NLC + l0) * NLQ;
  f32x4 acc[4][4] = {};
  for (int k0 = 0; k0 < NLQ; k0 += 32) {
    __syncthreads();
    {  // A: on-the-fly S_row from f32 S (rows l, K=m minor)
      int c = lane & 3;
      const int* qm = qmask + b * NLQ + k0 + c * 8;
#pragma unroll
      for (int i = 0; i < 2; ++i) {
        int seg = w + i * 4, r = seg * 16 + (lane >> 2);
        int l = l0 + r;
        const float* src = &Sb[(size_t)r * NLQ + k0 + c * 8];
        float4 v0 = *(const float4*)src;
        float4 v1 = *(const float4*)(src + 4);
        float mx = rmax[b * NLC + l], iv = rinv[b * NLC + l];
        short8 o;
        o[0] = bf16_of(expf(v0.x - mx) * iv * (float)qm[0]);
        o[1] = bf16_of(expf(v0.y - mx) * iv * (float)qm[1]);
        o[2] = bf16_of(expf(v0.z - mx) * iv * (float)qm[2]);
        o[3] = bf16_of(expf(v0.w - mx) * iv * (float)qm[3]);
        o[4] = bf16_of(expf(v1.x - mx) * iv * (float)qm[4]);
        o[5] = bf16_of(expf(v1.y - mx) * iv * (float)qm[5]);
        o[6] = bf16_of(expf(v1.z - mx) * iv * (float)qm[6]);
        o[7] = bf16_of(expf(v1.w - mx) * iv * (float)qm[7]);
        lds_w8(As, r, c, o);
      }
    }
    if (nb < 2) {  // B: reg-convert f32 Q (rows h, K=m minor)
      const float* Qb = Q + ((size_t)b * NH + nb * 128) * NLQ;
      int c = lane & 3;
#pragma unroll
      for (int i = 0; i < 2; ++i) {
        int seg = w + i * 4, r = seg * 16 + (lane >> 2);
        const float* src = &Qb[(size_t)r * NLQ + k0 + c * 8];
        float4 v0 = *(const float4*)src;
        float4 v1 = *(const float4*)(src + 4);
        lds_w8(Bs, r, c, cvt8(v0, v1));
      }
    } else {  // B: bf16 Tt via global_load_lds
      const short* Tb = Tt + ((size_t)b * NH + (nb - 2) * 128) * NLQ;
      stage_g(Tb + k0, NLQ, Bs, t);
    }
    __syncthreads();
    MFMA_STEP(As, Bs)
  }
  short* dst = (nb & 2) ? Bv_lh : A_lh;
  int hbase = (nb & 1) << 7;
#pragma unroll
  for (int mi = 0; mi < 4; ++mi)
#pragma unroll
    for (int ni = 0; ni < 4; ++ni)
#pragma unroll
      for (int r = 0; r < 4; ++r) {
        int l = l0 + wr + mi * 16 + g * 4 + r;
        int h = hbase + wc + ni * 16 + ln;
        dst[((size_t)b * NLC + l) * NH + h] = bf16_of(acc[mi][ni][r]);
      }
}

// -------- out[h][l] = relu(b + sum_f W[h][f]*cat[l][f])  (M=h, N=l, K=f) ------
__global__ __launch_bounds__(256) void k_out(
    const float* __restrict__ W, const short* __restrict__ Ct_lh,
    const short* __restrict__ A_lh, const short* __restrict__ Bv_lh,
    const float* __restrict__ br, float* __restrict__ out) {
  __shared__ short As[4096], Bs[4096];
  int b = blockIdx.z, h0 = blockIdx.y << 7, l0 = blockIdx.x << 7;
  GEMM_IDS
  f32x4 acc[4][4] = {};
  for (int k0 = 0; k0 < 4 * NH; k0 += 32) {
    __syncthreads();
    {  // A: reg-convert from f32 W (rows h, K=f minor)
      int c = lane & 3;
#pragma unroll
      for (int i = 0; i < 2; ++i) {
        int seg = w + i * 4, r = seg * 16 + (lane >> 2);
        const float* src = &W[(size_t)(h0 + r) * (4 * NH) + k0 + c * 8];
        float4 v0 = *(const float4*)src;
        float4 v1 = *(const float4*)(src + 4);
        lds_w8(As, r, c, cvt8(v0, v1));
      }
    }
    int reg = k0 >> 8, ko = k0 & 255;
    if (reg < 2) {  // B: Ct or A directly via global_load_lds
      const short* base = (reg == 0) ? Ct_lh : A_lh;
      stage_g(base + ((size_t)b * NLC + l0) * NH + ko, NH, Bs, t);
    } else {  // B: elementwise Ct * (A or Bv), reg-staged
      const short* base = (reg == 2) ? A_lh : Bv_lh;
      int c = lane & 3;
#pragma unroll
      for (int i = 0; i < 2; ++i) {
        int seg = w + i * 4, r = seg * 16 + (lane >> 2);
        size_t off = ((size_t)b * NLC + l0 + r) * NH + ko + c * 8;
        short8 x1 = *(const short8*)&Ct_lh[off];
        short8 x2 = *(const short8*)&base[off];
        short8 o;
#pragma unroll
        for (int j = 0; j < 8; ++j) o[j] = bf16_of(f_of(x1[j]) * f_of(x2[j]));
        lds_w8(Bs, r, c, o);
      }
    }
    __syncthreads();
    MFMA_STEP(As, Bs)
  }
#pragma unroll
  for (int mi = 0; mi < 4; ++mi)
#pragma unroll
    for (int ni = 0; ni < 4; ++ni) {
      int h = h0 + wr + mi * 16 + g * 4;
      int l = l0 + wc + ni * 16 + ln;
#pragma unroll
      for (int r = 0; r < 4; ++r) {
        float bias = br[h + r];
        out[((size_t)b * NH + h + r) * NLC + l] =
            fmaxf(acc[mi][ni][r] + bias, 0.f);
      }
    }
}

extern "C" void kernel_launch(void* const* d_in, const int* in_sizes, int n_in,
                              void* d_out, int out_size, void* d_ws,
                              size_t ws_size, hipStream_t stream) {
  (void)in_sizes;
  (void)n_in;
  (void)out_size;
  (void)ws_size;
  const float* C = (const float*)d_in[0];
  const float* Q = (const float*)d_in[1];
  const int* cmask = (const int*)d_in[2];
  const int* qmask = (const int*)d_in[3];
  const float* w = (const float*)d_in[4];
  const float* W = (const float*)d_in[5];
  const float* br = (const float*)d_in[6];
  float* out = (float*)d_out;

  char* p = (char*)d_ws;
  float* S = (float*)p;      p += (size_t)NB * NLC * NLQ * 4;   // 33.6 MB
  short* Ct_lh = (short*)p;  p += (size_t)NB * NLC * NH * 2;    // 16.8 MB
  short* A_lh = (short*)p;   p += (size_t)NB * NLC * NH * 2;    // 16.8 MB
  short* Bv_lh = (short*)p;  p += (size_t)NB * NLC * NH * 2;    // 16.8 MB
  short* Tt = (short*)p;     p += (size_t)NB * NH * NLQ * 2;    // 4.2 MB
  short* Qtw3 = (short*)p;   p += (size_t)NB * NLQ * NH * 2;    // 4.2 MB
  float* s1 = (float*)p;     p += (size_t)NB * NLC * 4;
  float* s2 = (float*)p;     p += (size_t)NB * NLQ * 4;
  float* rmax = (float*)p;   p += (size_t)NB * NLC * 4;
  float* rinv = (float*)p;   p += (size_t)NB * NLC * 4;
  float* cmax = (float*)p;   p += (size_t)NB * NLQ * 4;
  float* cinv = (float*)p;   p += (size_t)NB * NLQ * 4;

  k_prep_c<<<dim3(NLC / 64, NH / 64, NB), dim3(256), 0, stream>>>(C, Ct_lh);
  k_prep_q<<<dim3(NLQ / 64, NH / 64, NB), dim3(256), 0, stream>>>(Q, w, Qtw3);
  k_s1<<<dim3(NB * (NLC / 256)), dim3(256), 0, stream>>>(C, w, s1);
  k_s2<<<dim3(NB), dim3(256), 0, stream>>>(Q, w, s2);
  k_sgemm<<<dim3(NLQ / 128, NLC / 128, NB), dim3(256), 0, stream>>>(
      Ct_lh, Qtw3, s1, s2, S);
  k_rowstats<<<dim3(NB * NLC / 4), dim3(256), 0, stream>>>(S, qmask, rmax,
                                                           rinv);
  k_colstats<<<dim3(NB * (NLQ / 64)), dim3(256), 0, stream>>>(S, cmask, cmax,
                                                              cinv);
  k_tgemm<<<dim3(NLQ / 128, NH / 128, NB), dim3(256), 0, stream>>>(
      C, S, cmask, cmax, cinv, Tt);
  k_abgemm<<<dim3(4, NLC / 128, NB), dim3(256), 0, stream>>>(
      S, Q, Tt, qmask, rmax, rinv, A_lh, Bv_lh);
  k_out<<<dim3(NLC / 128, NH / 128, NB), dim3(256), 0, stream>>>(
      W, Ct_lh, A_lh, Bv_lh, br, out);
}

// Round 3
// 219.246 us; speedup vs baseline: 3.0152x; 1.3458x over previous
//
#include <hip/hip_runtime.h>
#include <math.h>

#define NB 32
#define NH 256
#define NLC 1024
#define NLQ 256
#define NEGV (-1e30f)
#define LCHUNK 16  // column-stats l-chunks (each 64 rows)

typedef short short8 __attribute__((ext_vector_type(8)));
typedef float f32x4 __attribute__((ext_vector_type(4)));

__device__ inline short bf16_of(float f) {
  union { float f; unsigned u; } v;
  v.f = f;
  unsigned r = (v.u + 0x7fffu + ((v.u >> 16) & 1u)) >> 16;
  return (short)r;
}
__device__ inline float f_of(short s) {
  union { unsigned u; float f; } v;
  v.u = ((unsigned)(unsigned short)s) << 16;
  return v.f;
}
__device__ inline short8 cvt8(float4 a, float4 b) {
  short8 o;
  o[0] = bf16_of(a.x); o[1] = bf16_of(a.y); o[2] = bf16_of(a.z); o[3] = bf16_of(a.w);
  o[4] = bf16_of(b.x); o[5] = bf16_of(b.y); o[6] = bf16_of(b.z); o[7] = bf16_of(b.w);
  return o;
}

// ---- swizzled 128x32 bf16 LDS tile helpers (row = 64B, slot ^= (row>>1)&3) ----
__device__ inline void lds_w8(short* lds, int r, int c, short8 v) {
  int byteoff = (r << 6) + (((c ^ ((r >> 1) & 3)) & 3) << 4);
  *(short8*)((char*)lds + byteoff) = v;
}
__device__ inline short8 lds_r8(const short* lds, int R, int g) {
  int byteoff = (R << 6) + (((g ^ ((R >> 1) & 3)) & 3) << 4);
  return *(const short8*)((const char*)lds + byteoff);
}
// global_load_lds staging of a 128x32 bf16 tile from K-minor src (ld elements).
// Source pre-permuted so linear LDS bytes match the swizzled-read layout.
__device__ inline void stage_g(const short* src, int ld, short* lds, int t) {
  int L = t & 63, w = t >> 6;
  int cp = (L & 3) ^ ((L >> 3) & 3);
#pragma unroll
  for (int i = 0; i < 2; ++i) {
    int seg = w + i * 4;
    const short* g = src + (size_t)(seg * 16 + (L >> 2)) * ld + cp * 8;
    __builtin_amdgcn_global_load_lds(
        (const __attribute__((address_space(1))) unsigned int*)g,
        (__attribute__((address_space(3))) unsigned int*)(lds + seg * 512), 16,
        0, 0);
  }
}

#define GEMM_IDS                                       \
  int t = threadIdx.x, lane = t & 63, w = t >> 6;      \
  int ln = lane & 15, g = lane >> 4;                   \
  int wr = (w >> 1) << 6, wc = (w & 1) << 6;           \
  (void)wr; (void)wc;

#define MFMA_STEP(AS, BS)                                                      \
  {                                                                            \
    short8 af[4], bfr[4];                                                      \
    _Pragma("unroll") for (int mi = 0; mi < 4; ++mi) af[mi] =                  \
        lds_r8(AS, wr + mi * 16 + ln, g);                                      \
    _Pragma("unroll") for (int ni = 0; ni < 4; ++ni) bfr[ni] =                 \
        lds_r8(BS, wc + ni * 16 + ln, g);                                      \
    _Pragma("unroll") for (int mi = 0; mi < 4; ++mi)                           \
        _Pragma("unroll") for (int ni = 0; ni < 4; ++ni) acc[mi][ni] =         \
            __builtin_amdgcn_mfma_f32_16x16x32_bf16(af[mi], bfr[ni],           \
                                                    acc[mi][ni], 0, 0, 0);     \
  }

// ---------------- prep: Ct_lh[l][h] = bf16(C[h][l]) ----------------
__global__ __launch_bounds__(256) void k_prep_c(const float* __restrict__ C,
                                                short* __restrict__ Ct_lh) {
  __shared__ float Ts[64][65];
  int b = blockIdx.z, h0 = blockIdx.y << 6, l0 = blockIdx.x << 6;
  int t = threadIdx.x;
  int hr = t >> 4, lc = (t & 15) << 2;
  const float* Cb = C + ((size_t)b * NH + h0) * NLC + l0;
#pragma unroll
  for (int i = 0; i < 4; ++i) {
    float4 v = *(const float4*)&Cb[(size_t)(hr + i * 16) * NLC + lc];
    Ts[hr + i * 16][lc + 0] = v.x;
    Ts[hr + i * 16][lc + 1] = v.y;
    Ts[hr + i * 16][lc + 2] = v.z;
    Ts[hr + i * 16][lc + 3] = v.w;
  }
  __syncthreads();
  int lr = t >> 2, hc = (t & 3) << 4;
  short* dst = &Ct_lh[((size_t)b * NLC + l0 + lr) * NH + h0 + hc];
  short8 o0, o1;
#pragma unroll
  for (int j = 0; j < 8; ++j) o0[j] = bf16_of(Ts[hc + j][lr]);
#pragma unroll
  for (int j = 0; j < 8; ++j) o1[j] = bf16_of(Ts[hc + 8 + j][lr]);
  *(short8*)dst = o0;
  *(short8*)(dst + 8) = o1;
}

// ---------------- prep: Qtw3[m][h] = bf16(Q[h][m]*w3[h]) ----------------
__global__ __launch_bounds__(256) void k_prep_q(const float* __restrict__ Q,
                                                const float* __restrict__ w,
                                                short* __restrict__ Qtw3) {
  __shared__ float Ts[64][65];
  int b = blockIdx.z, h0 = blockIdx.y << 6, m0 = blockIdx.x << 6;
  int t = threadIdx.x;
  int hr = t >> 4, mc = (t & 15) << 2;
  const float* w3 = w + 2 * NH;
  const float* Qb = Q + ((size_t)b * NH + h0) * NLQ + m0;
#pragma unroll
  for (int i = 0; i < 4; ++i) {
    int h = hr + i * 16;
    float w3v = w3[h0 + h];
    float4 v = *(const float4*)&Qb[(size_t)h * NLQ + mc];
    Ts[h][mc + 0] = v.x * w3v;
    Ts[h][mc + 1] = v.y * w3v;
    Ts[h][mc + 2] = v.z * w3v;
    Ts[h][mc + 3] = v.w * w3v;
  }
  __syncthreads();
  int mr = t >> 2, hc = (t & 3) << 4;
  short* dst = &Qtw3[((size_t)b * NLQ + m0 + mr) * NH + h0 + hc];
  short8 o0, o1;
#pragma unroll
  for (int j = 0; j < 8; ++j) o0[j] = bf16_of(Ts[hc + j][mr]);
#pragma unroll
  for (int j = 0; j < 8; ++j) o1[j] = bf16_of(Ts[hc + 8 + j][mr]);
  *(short8*)dst = o0;
  *(short8*)(dst + 8) = o1;
}

// s1[b][l] = sum_h C[b][h][l] * w1[h]
__global__ __launch_bounds__(256) void k_s1(const float* __restrict__ C,
                                            const float* __restrict__ w,
                                            float* __restrict__ s1) {
  int b = blockIdx.x >> 2;
  int l = ((blockIdx.x & 3) << 8) + threadIdx.x;
  const float* Cb = C + (size_t)b * NH * NLC;
  float acc = 0.f;
#pragma unroll 8
  for (int h = 0; h < NH; ++h) acc += Cb[(size_t)h * NLC + l] * w[h];
  s1[b * NLC + l] = acc;
}

// s2[b][m] = sum_h Q[b][h][m] * w2[h]
__global__ __launch_bounds__(256) void k_s2(const float* __restrict__ Q,
                                            const float* __restrict__ w,
                                            float* __restrict__ s2) {
  int b = blockIdx.x;
  int m = threadIdx.x;
  const float* Qb = Q + (size_t)b * NH * NLQ;
  const float* w2 = w + NH;
  float acc = 0.f;
#pragma unroll 8
  for (int h = 0; h < NH; ++h) acc += Qb[(size_t)h * NLQ + m] * w2[h];
  s2[b * NLQ + m] = acc;
}

// ---------------- S = Ct_lh @ Qtw3^T + s1 + s2  (M=l, N=m, K=h) ----------------
__global__ __launch_bounds__(256) void k_sgemm(
    const short* __restrict__ Ct_lh, const short* __restrict__ Qtw3,
    const float* __restrict__ s1, const float* __restrict__ s2,
    float* __restrict__ S) {
  __shared__ short As[4096], Bs[4096];
  int b = blockIdx.z, l0 = blockIdx.y << 7, m0 = blockIdx.x << 7;
  GEMM_IDS
  const short* Ag = Ct_lh + ((size_t)b * NLC + l0) * NH;
  const short* Bg = Qtw3 + ((size_t)b * NLQ + m0) * NH;
  f32x4 acc[4][4] = {};
  for (int k0 = 0; k0 < NH; k0 += 32) {
    __syncthreads();
    stage_g(Ag + k0, NH, As, t);
    stage_g(Bg + k0, NH, Bs, t);
    __syncthreads();
    MFMA_STEP(As, Bs)
  }
#pragma unroll
  for (int mi = 0; mi < 4; ++mi)
#pragma unroll
    for (int ni = 0; ni < 4; ++ni)
#pragma unroll
      for (int r = 0; r < 4; ++r) {
        int l = l0 + wr + mi * 16 + g * 4 + r;
        int m = m0 + wc + ni * 16 + ln;
        S[((size_t)b * NLC + l) * NLQ + m] =
            acc[mi][ni][r] + s1[b * NLC + l] + s2[b * NLQ + m];
      }
}

// per-row (over m) masked max & inverse-sum-exp. One wave per row.
__global__ __launch_bounds__(256) void k_rowstats(const float* __restrict__ S,
                                                  const int* __restrict__ qmask,
                                                  float* __restrict__ rmax,
                                                  float* __restrict__ rinv) {
  int wave = threadIdx.x >> 6, lane = threadIdx.x & 63;
  int idx = (blockIdx.x << 2) + wave;
  int b = idx >> 10;
  const float* row = S + (size_t)idx * NLQ;
  const int* qm = qmask + b * NLQ;
  float v[4], mx = -INFINITY;
#pragma unroll
  for (int i = 0; i < 4; ++i) {
    int m = lane + (i << 6);
    float x = row[m] + (qm[m] ? 0.f : NEGV);
    v[i] = x;
    mx = fmaxf(mx, x);
  }
#pragma unroll
  for (int off = 32; off > 0; off >>= 1) mx = fmaxf(mx, __shfl_xor(mx, off));
  float sm = 0.f;
#pragma unroll
  for (int i = 0; i < 4; ++i) sm += expf(v[i] - mx);
#pragma unroll
  for (int off = 32; off > 0; off >>= 1) sm += __shfl_xor(sm, off);
  if (lane == 0) {
    rmax[idx] = mx;
    rinv[idx] = 1.0f / sm;
  }
}

// per-column (over l) masked max & sum-exp partials, one 64-row chunk per block.
__global__ __launch_bounds__(256) void k_colpart(const float* __restrict__ S,
                                                 const int* __restrict__ cmask,
                                                 float* __restrict__ pmax,
                                                 float* __restrict__ psum) {
  int idx = blockIdx.x;  // ((b*4 + mb)*LCHUNK + chunk)
  int chunk = idx & (LCHUNK - 1);
  int mb = (idx >> 4) & 3;
  int b = idx >> 6;
  int m0 = mb << 6;
  int tx = threadIdx.x & 63, ty = threadIdx.x >> 6;
  const float* Sb = S + (size_t)b * NLC * NLQ + (size_t)(chunk * 64) * NLQ;
  const int* cm = cmask + b * NLC + chunk * 64;
  float mx = -INFINITY, sm = 0.f;
#pragma unroll 4
  for (int l = ty; l < 64; l += 4) {
    float x = Sb[(size_t)l * NLQ + m0 + tx] + (cm[l] ? 0.f : NEGV);
    float nmx = fmaxf(mx, x);
    sm = sm * expf(mx - nmx) + expf(x - nmx);
    mx = nmx;
  }
  __shared__ float smx[4][64], ssm[4][64];
  smx[ty][tx] = mx;
  ssm[ty][tx] = sm;
  __syncthreads();
  if (ty == 0) {
#pragma unroll
    for (int r = 1; r < 4; ++r) {
      float m2 = smx[r][tx], s2 = ssm[r][tx];
      float nm = fmaxf(mx, m2);
      sm = sm * expf(mx - nm) + s2 * expf(m2 - nm);
      mx = nm;
    }
    int m = (b << 8) + m0 + tx;  // global column id
    pmax[(size_t)m * LCHUNK + chunk] = mx;
    psum[(size_t)m * LCHUNK + chunk] = sm;
  }
}

// combine LCHUNK partials per column -> cmax, cinv. One thread per column.
__global__ __launch_bounds__(256) void k_colfin(const float* __restrict__ pmax,
                                                const float* __restrict__ psum,
                                                float* __restrict__ cmax,
                                                float* __restrict__ cinv) {
  int m = blockIdx.x * 256 + threadIdx.x;  // [0, NB*NLQ)
  const float* pm = pmax + (size_t)m * LCHUNK;
  const float* ps = psum + (size_t)m * LCHUNK;
  float mx = pm[0], sm = ps[0];
#pragma unroll
  for (int c = 1; c < LCHUNK; ++c) {
    float m2 = pm[c], s2 = ps[c];
    float nm = fmaxf(mx, m2);
    sm = sm * expf(mx - nm) + s2 * expf(m2 - nm);
    mx = nm;
  }
  cmax[m] = mx;
  cinv[m] = 1.0f / sm;
}

// ---------------- Tt[h][m] = sum_l C[h][l] * S_col[l][m]  (M=h, N=m, K=l) -----
__global__ __launch_bounds__(256) void k_tgemm(
    const float* __restrict__ C, const float* __restrict__ S,
    const int* __restrict__ cmask, const float* __restrict__ cmax,
    const float* __restrict__ cinv, short* __restrict__ Tt) {
  __shared__ short As[4096], Bs[4096];
  int b = blockIdx.z, h0 = blockIdx.y << 7, m0 = blockIdx.x << 7;
  GEMM_IDS
  const float* Cb = C + ((size_t)b * NH + h0) * NLC;
  const float* Sb = S + (size_t)b * NLC * NLQ;
  const float* cmx = cmax + b * NLQ + m0;
  const float* civ = cinv + b * NLQ + m0;
  const int* cm = cmask + b * NLC;
  f32x4 acc[4][4] = {};
  for (int k0 = 0; k0 < NLC; k0 += 32) {
    __syncthreads();
    {  // A: reg-convert from f32 C (rows h, K=l minor)
      int c = lane & 3;
#pragma unroll
      for (int i = 0; i < 2; ++i) {
        int seg = w + i * 4, r = seg * 16 + (lane >> 2);
        const float* src = &Cb[(size_t)r * NLC + k0 + c * 8];
        float4 v0 = *(const float4*)src;
        float4 v1 = *(const float4*)(src + 4);
        lds_w8(As, r, c, cvt8(v0, v1));
      }
    }
    {  // B: transposing exp-staging from f32 S (rows m, K=l)
      int lloc = t >> 3, l = k0 + lloc;
      float cmf = (float)cm[l];
      const float* srow = &Sb[(size_t)l * NLQ + m0];
      int g2 = lloc >> 3, kin = lloc & 7;
#pragma unroll
      for (int mi4 = 0; mi4 < 4; ++mi4) {
        int m = ((t & 7) << 2) + (mi4 << 5);
        float4 sv = *(const float4*)&srow[m];
        float p[4];
        p[0] = expf(sv.x - cmx[m + 0]) * civ[m + 0] * cmf;
        p[1] = expf(sv.y - cmx[m + 1]) * civ[m + 1] * cmf;
        p[2] = expf(sv.z - cmx[m + 2]) * civ[m + 2] * cmf;
        p[3] = expf(sv.w - cmx[m + 3]) * civ[m + 3] * cmf;
#pragma unroll
        for (int j = 0; j < 4; ++j) {
          int R = m + j;
          int byteoff =
              (R << 6) + (((g2 ^ ((R >> 1) & 3)) & 3) << 4) + (kin << 1);
          *(short*)((char*)Bs + byteoff) = bf16_of(p[j]);
        }
      }
    }
    __syncthreads();
    MFMA_STEP(As, Bs)
  }
#pragma unroll
  for (int mi = 0; mi < 4; ++mi)
#pragma unroll
    for (int ni = 0; ni < 4; ++ni)
#pragma unroll
      for (int r = 0; r < 4; ++r) {
        int h = h0 + wr + mi * 16 + g * 4 + r;
        int m = m0 + wc + ni * 16 + ln;
        Tt[((size_t)b * NH + h) * NLQ + m] = bf16_of(acc[mi][ni][r]);
      }
}

// -------- [A|Bv][l][h] = sum_m S_row[l][m] * X[h][m]  (M=l, N=h', K=m) --------
__global__ __launch_bounds__(256) void k_abgemm(
    const float* __restrict__ S, const float* __restrict__ Q,
    const short* __restrict__ Tt, const int* __restrict__ qmask,
    const float* __restrict__ rmax, const float* __restrict__ rinv,
    short* __restrict__ A_lh, short* __restrict__ Bv_lh) {
  __shared__ short As[4096], Bs[4096];
  int b = blockIdx.z, l0 = blockIdx.y << 7, nb = blockIdx.x;
  GEMM_IDS
  const float* Sb = S + ((size_t)b * NLC + l0) * NLQ;
  f32x4 acc[4][4] = {};
  for (int k0 = 0; k0 < NLQ; k0 += 32) {
    __syncthreads();
    {  // A: on-the-fly S_row from f32 S (rows l, K=m minor)
      int c = lane & 3;
      const int* qm = qmask + b * NLQ + k0 + c * 8;
#pragma unroll
      for (int i = 0; i < 2; ++i) {
        int seg = w + i * 4, r = seg * 16 + (lane >> 2);
        int l = l0 + r;
        const float* src = &Sb[(size_t)r * NLQ + k0 + c * 8];
        float4 v0 = *(const float4*)src;
        float4 v1 = *(const float4*)(src + 4);
        float mx = rmax[b * NLC + l], iv = rinv[b * NLC + l];
        short8 o;
        o[0] = bf16_of(expf(v0.x - mx) * iv * (float)qm[0]);
        o[1] = bf16_of(expf(v0.y - mx) * iv * (float)qm[1]);
        o[2] = bf16_of(expf(v0.z - mx) * iv * (float)qm[2]);
        o[3] = bf16_of(expf(v0.w - mx) * iv * (float)qm[3]);
        o[4] = bf16_of(expf(v1.x - mx) * iv * (float)qm[4]);
        o[5] = bf16_of(expf(v1.y - mx) * iv * (float)qm[5]);
        o[6] = bf16_of(expf(v1.z - mx) * iv * (float)qm[6]);
        o[7] = bf16_of(expf(v1.w - mx) * iv * (float)qm[7]);
        lds_w8(As, r, c, o);
      }
    }
    if (nb < 2) {  // B: reg-convert f32 Q (rows h, K=m minor)
      const float* Qb = Q + ((size_t)b * NH + nb * 128) * NLQ;
      int c = lane & 3;
#pragma unroll
      for (int i = 0; i < 2; ++i) {
        int seg = w + i * 4, r = seg * 16 + (lane >> 2);
        const float* src = &Qb[(size_t)r * NLQ + k0 + c * 8];
        float4 v0 = *(const float4*)src;
        float4 v1 = *(const float4*)(src + 4);
        lds_w8(Bs, r, c, cvt8(v0, v1));
      }
    } else {  // B: bf16 Tt via global_load_lds
      const short* Tb = Tt + ((size_t)b * NH + (nb - 2) * 128) * NLQ;
      stage_g(Tb + k0, NLQ, Bs, t);
    }
    __syncthreads();
    MFMA_STEP(As, Bs)
  }
  short* dst = (nb & 2) ? Bv_lh : A_lh;
  int hbase = (nb & 1) << 7;
#pragma unroll
  for (int mi = 0; mi < 4; ++mi)
#pragma unroll
    for (int ni = 0; ni < 4; ++ni)
#pragma unroll
      for (int r = 0; r < 4; ++r) {
        int l = l0 + wr + mi * 16 + g * 4 + r;
        int h = hbase + wc + ni * 16 + ln;
        dst[((size_t)b * NLC + l) * NH + h] = bf16_of(acc[mi][ni][r]);
      }
}

// -------- out[h][l] = relu(b + sum_f W[h][f]*cat[l][f])  (M=h, N=l, K=f) ------
__global__ __launch_bounds__(256) void k_out(
    const float* __restrict__ W, const short* __restrict__ Ct_lh,
    const short* __restrict__ A_lh, const short* __restrict__ Bv_lh,
    const float* __restrict__ br, float* __restrict__ out) {
  __shared__ short As[4096], Bs[4096];
  int b = blockIdx.z, h0 = blockIdx.y << 7, l0 = blockIdx.x << 7;
  GEMM_IDS
  f32x4 acc[4][4] = {};
  for (int k0 = 0; k0 < 4 * NH; k0 += 32) {
    __syncthreads();
    {  // A: reg-convert from f32 W (rows h, K=f minor)
      int c = lane & 3;
#pragma unroll
      for (int i = 0; i < 2; ++i) {
        int seg = w + i * 4, r = seg * 16 + (lane >> 2);
        const float* src = &W[(size_t)(h0 + r) * (4 * NH) + k0 + c * 8];
        float4 v0 = *(const float4*)src;
        float4 v1 = *(const float4*)(src + 4);
        lds_w8(As, r, c, cvt8(v0, v1));
      }
    }
    int reg = k0 >> 8, ko = k0 & 255;
    if (reg < 2) {  // B: Ct or A directly via global_load_lds
      const short* base = (reg == 0) ? Ct_lh : A_lh;
      stage_g(base + ((size_t)b * NLC + l0) * NH + ko, NH, Bs, t);
    } else {  // B: elementwise Ct * (A or Bv), reg-staged
      const short* base = (reg == 2) ? A_lh : Bv_lh;
      int c = lane & 3;
#pragma unroll
      for (int i = 0; i < 2; ++i) {
        int seg = w + i * 4, r = seg * 16 + (lane >> 2);
        size_t off = ((size_t)b * NLC + l0 + r) * NH + ko + c * 8;
        short8 x1 = *(const short8*)&Ct_lh[off];
        short8 x2 = *(const short8*)&base[off];
        short8 o;
#pragma unroll
        for (int j = 0; j < 8; ++j) o[j] = bf16_of(f_of(x1[j]) * f_of(x2[j]));
        lds_w8(Bs, r, c, o);
      }
    }
    __syncthreads();
    MFMA_STEP(As, Bs)
  }
#pragma unroll
  for (int mi = 0; mi < 4; ++mi)
#pragma unroll
    for (int ni = 0; ni < 4; ++ni) {
      int h = h0 + wr + mi * 16 + g * 4;
      int l = l0 + wc + ni * 16 + ln;
#pragma unroll
      for (int r = 0; r < 4; ++r) {
        float bias = br[h + r];
        out[((size_t)b * NH + h + r) * NLC + l] =
            fmaxf(acc[mi][ni][r] + bias, 0.f);
      }
    }
}

extern "C" void kernel_launch(void* const* d_in, const int* in_sizes, int n_in,
                              void* d_out, int out_size, void* d_ws,
                              size_t ws_size, hipStream_t stream) {
  (void)in_sizes;
  (void)n_in;
  (void)out_size;
  (void)ws_size;
  const float* C = (const float*)d_in[0];
  const float* Q = (const float*)d_in[1];
  const int* cmask = (const int*)d_in[2];
  const int* qmask = (const int*)d_in[3];
  const float* w = (const float*)d_in[4];
  const float* W = (const float*)d_in[5];
  const float* br = (const float*)d_in[6];
  float* out = (float*)d_out;

  char* p = (char*)d_ws;
  float* S = (float*)p;      p += (size_t)NB * NLC * NLQ * 4;   // 33.6 MB
  short* Ct_lh = (short*)p;  p += (size_t)NB * NLC * NH * 2;    // 16.8 MB
  short* A_lh = (short*)p;   p += (size_t)NB * NLC * NH * 2;    // 16.8 MB
  short* Bv_lh = (short*)p;  p += (size_t)NB * NLC * NH * 2;    // 16.8 MB
  short* Tt = (short*)p;     p += (size_t)NB * NH * NLQ * 2;    // 4.2 MB
  short* Qtw3 = (short*)p;   p += (size_t)NB * NLQ * NH * 2;    // 4.2 MB
  float* s1 = (float*)p;     p += (size_t)NB * NLC * 4;
  float* s2 = (float*)p;     p += (size_t)NB * NLQ * 4;
  float* rmax = (float*)p;   p += (size_t)NB * NLC * 4;
  float* rinv = (float*)p;   p += (size_t)NB * NLC * 4;
  float* cmax = (float*)p;   p += (size_t)NB * NLQ * 4;
  float* cinv = (float*)p;   p += (size_t)NB * NLQ * 4;
  float* pmax = (float*)p;   p += (size_t)NB * NLQ * LCHUNK * 4;
  float* psum = (float*)p;   p += (size_t)NB * NLQ * LCHUNK * 4;

  k_prep_c<<<dim3(NLC / 64, NH / 64, NB), dim3(256), 0, stream>>>(C, Ct_lh);
  k_prep_q<<<dim3(NLQ / 64, NH / 64, NB), dim3(256), 0, stream>>>(Q, w, Qtw3);
  k_s1<<<dim3(NB * (NLC / 256)), dim3(256), 0, stream>>>(C, w, s1);
  k_s2<<<dim3(NB), dim3(256), 0, stream>>>(Q, w, s2);
  k_sgemm<<<dim3(NLQ / 128, NLC / 128, NB), dim3(256), 0, stream>>>(
      Ct_lh, Qtw3, s1, s2, S);
  k_rowstats<<<dim3(NB * NLC / 4), dim3(256), 0, stream>>>(S, qmask, rmax,
                                                           rinv);
  k_colpart<<<dim3(NB * 4 * LCHUNK), dim3(256), 0, stream>>>(S, cmask, pmax,
                                                             psum);
  k_colfin<<<dim3(NB * NLQ / 256), dim3(256), 0, stream>>>(pmax, psum, cmax,
                                                           cinv);
  k_tgemm<<<dim3(NLQ / 128, NH / 128, NB), dim3(256), 0, stream>>>(
      C, S, cmask, cmax, cinv, Tt);
  k_abgemm<<<dim3(4, NLC / 128, NB), dim3(256), 0, stream>>>(
      S, Q, Tt, qmask, rmax, rinv, A_lh, Bv_lh);
  k_out<<<dim3(NLC / 128, NH / 128, NB), dim3(256), 0, stream>>>(
      W, Ct_lh, A_lh, Bv_lh, br, out);
}

// Round 4
// 193.606 us; speedup vs baseline: 3.4145x; 1.1324x over previous
//
#include <hip/hip_runtime.h>
#include <math.h>

#define NB 32
#define NH 256
#define NLC 1024
#define NLQ 256
#define NEGV (-1e30f)
#define LCHUNK 16  // column-stats l-chunks (each 64 rows)
#define KSPLIT 4   // tgemm split-K factor

typedef short short8 __attribute__((ext_vector_type(8)));
typedef float f32x4 __attribute__((ext_vector_type(4)));

__device__ inline short bf16_of(float f) {
  union { float f; unsigned u; } v;
  v.f = f;
  unsigned r = (v.u + 0x7fffu + ((v.u >> 16) & 1u)) >> 16;
  return (short)r;
}
__device__ inline float f_of(short s) {
  union { unsigned u; float f; } v;
  v.u = ((unsigned)(unsigned short)s) << 16;
  return v.f;
}
__device__ inline short8 cvt8(float4 a, float4 b) {
  short8 o;
  o[0] = bf16_of(a.x); o[1] = bf16_of(a.y); o[2] = bf16_of(a.z); o[3] = bf16_of(a.w);
  o[4] = bf16_of(b.x); o[5] = bf16_of(b.y); o[6] = bf16_of(b.z); o[7] = bf16_of(b.w);
  return o;
}

// ---- swizzled 128x32 bf16 LDS tile helpers (row = 64B, slot ^= (row>>1)&3) ----
__device__ inline void lds_w8(short* lds, int r, int c, short8 v) {
  int byteoff = (r << 6) + (((c ^ ((r >> 1) & 3)) & 3) << 4);
  *(short8*)((char*)lds + byteoff) = v;
}
__device__ inline short8 lds_r8(const short* lds, int R, int g) {
  int byteoff = (R << 6) + (((g ^ ((R >> 1) & 3)) & 3) << 4);
  return *(const short8*)((const char*)lds + byteoff);
}
// global_load_lds staging of a 128x32 bf16 tile from K-minor src (ld elements).
// Source pre-permuted so linear LDS bytes match the swizzled-read layout.
__device__ inline void stage_g(const short* src, int ld, short* lds, int t) {
  int L = t & 63, w = t >> 6;
  int cp = (L & 3) ^ ((L >> 3) & 3);
#pragma unroll
  for (int i = 0; i < 2; ++i) {
    int seg = w + i * 4;
    const short* g = src + (size_t)(seg * 16 + (L >> 2)) * ld + cp * 8;
    __builtin_amdgcn_global_load_lds(
        (const __attribute__((address_space(1))) unsigned int*)g,
        (__attribute__((address_space(3))) unsigned int*)(lds + seg * 512), 16,
        0, 0);
  }
}

#define GEMM_IDS                                       \
  int t = threadIdx.x, lane = t & 63, w = t >> 6;      \
  int ln = lane & 15, g = lane >> 4;                   \
  int wr = (w >> 1) << 6, wc = (w & 1) << 6;           \
  (void)wr; (void)wc;

#define MFMA_STEP(AS, BS)                                                      \
  {                                                                            \
    short8 af[4], bfr[4];                                                      \
    _Pragma("unroll") for (int mi = 0; mi < 4; ++mi) af[mi] =                  \
        lds_r8(AS, wr + mi * 16 + ln, g);                                      \
    _Pragma("unroll") for (int ni = 0; ni < 4; ++ni) bfr[ni] =                 \
        lds_r8(BS, wc + ni * 16 + ln, g);                                      \
    _Pragma("unroll") for (int mi = 0; mi < 4; ++mi)                           \
        _Pragma("unroll") for (int ni = 0; ni < 4; ++ni) acc[mi][ni] =         \
            __builtin_amdgcn_mfma_f32_16x16x32_bf16(af[mi], bfr[ni],           \
                                                    acc[mi][ni], 0, 0, 0);     \
  }

// ---------------- prep: Ct_lh[l][h] = bf16(C[h][l]) ----------------
__global__ __launch_bounds__(256) void k_prep_c(const float* __restrict__ C,
                                                short* __restrict__ Ct_lh) {
  __shared__ float Ts[64][65];
  int b = blockIdx.z, h0 = blockIdx.y << 6, l0 = blockIdx.x << 6;
  int t = threadIdx.x;
  int hr = t >> 4, lc = (t & 15) << 2;
  const float* Cb = C + ((size_t)b * NH + h0) * NLC + l0;
#pragma unroll
  for (int i = 0; i < 4; ++i) {
    float4 v = *(const float4*)&Cb[(size_t)(hr + i * 16) * NLC + lc];
    Ts[hr + i * 16][lc + 0] = v.x;
    Ts[hr + i * 16][lc + 1] = v.y;
    Ts[hr + i * 16][lc + 2] = v.z;
    Ts[hr + i * 16][lc + 3] = v.w;
  }
  __syncthreads();
  int lr = t >> 2, hc = (t & 3) << 4;
  short* dst = &Ct_lh[((size_t)b * NLC + l0 + lr) * NH + h0 + hc];
  short8 o0, o1;
#pragma unroll
  for (int j = 0; j < 8; ++j) o0[j] = bf16_of(Ts[hc + j][lr]);
#pragma unroll
  for (int j = 0; j < 8; ++j) o1[j] = bf16_of(Ts[hc + 8 + j][lr]);
  *(short8*)dst = o0;
  *(short8*)(dst + 8) = o1;
}

// ---------------- prep: Qtw3[m][h] = bf16(Q[h][m]*w3[h]) ----------------
__global__ __launch_bounds__(256) void k_prep_q(const float* __restrict__ Q,
                                                const float* __restrict__ w,
                                                short* __restrict__ Qtw3) {
  __shared__ float Ts[64][65];
  int b = blockIdx.z, h0 = blockIdx.y << 6, m0 = blockIdx.x << 6;
  int t = threadIdx.x;
  int hr = t >> 4, mc = (t & 15) << 2;
  const float* w3 = w + 2 * NH;
  const float* Qb = Q + ((size_t)b * NH + h0) * NLQ + m0;
#pragma unroll
  for (int i = 0; i < 4; ++i) {
    int h = hr + i * 16;
    float w3v = w3[h0 + h];
    float4 v = *(const float4*)&Qb[(size_t)h * NLQ + mc];
    Ts[h][mc + 0] = v.x * w3v;
    Ts[h][mc + 1] = v.y * w3v;
    Ts[h][mc + 2] = v.z * w3v;
    Ts[h][mc + 3] = v.w * w3v;
  }
  __syncthreads();
  int mr = t >> 2, hc = (t & 3) << 4;
  short* dst = &Qtw3[((size_t)b * NLQ + m0 + mr) * NH + h0 + hc];
  short8 o0, o1;
#pragma unroll
  for (int j = 0; j < 8; ++j) o0[j] = bf16_of(Ts[hc + j][mr]);
#pragma unroll
  for (int j = 0; j < 8; ++j) o1[j] = bf16_of(Ts[hc + 8 + j][mr]);
  *(short8*)dst = o0;
  *(short8*)(dst + 8) = o1;
}

// s1[b][l] = sum_h C[b][h][l] * w1[h]
__global__ __launch_bounds__(256) void k_s1(const float* __restrict__ C,
                                            const float* __restrict__ w,
                                            float* __restrict__ s1) {
  int b = blockIdx.x >> 2;
  int l = ((blockIdx.x & 3) << 8) + threadIdx.x;
  const float* Cb = C + (size_t)b * NH * NLC;
  float acc = 0.f;
#pragma unroll 8
  for (int h = 0; h < NH; ++h) acc += Cb[(size_t)h * NLC + l] * w[h];
  s1[b * NLC + l] = acc;
}

// s2[b][m] = sum_h Q[b][h][m] * w2[h]
__global__ __launch_bounds__(256) void k_s2(const float* __restrict__ Q,
                                            const float* __restrict__ w,
                                            float* __restrict__ s2) {
  int b = blockIdx.x;
  int m = threadIdx.x;
  const float* Qb = Q + (size_t)b * NH * NLQ;
  const float* w2 = w + NH;
  float acc = 0.f;
#pragma unroll 8
  for (int h = 0; h < NH; ++h) acc += Qb[(size_t)h * NLQ + m] * w2[h];
  s2[b * NLQ + m] = acc;
}

// ---------------- S = Ct_lh @ Qtw3^T + s1 + s2  (M=l, N=m, K=h) ----------------
__global__ __launch_bounds__(256) void k_sgemm(
    const short* __restrict__ Ct_lh, const short* __restrict__ Qtw3,
    const float* __restrict__ s1, const float* __restrict__ s2,
    float* __restrict__ S) {
  __shared__ short As[4096], Bs[4096];
  int b = blockIdx.z, l0 = blockIdx.y << 7, m0 = blockIdx.x << 7;
  GEMM_IDS
  const short* Ag = Ct_lh + ((size_t)b * NLC + l0) * NH;
  const short* Bg = Qtw3 + ((size_t)b * NLQ + m0) * NH;
  f32x4 acc[4][4] = {};
  for (int k0 = 0; k0 < NH; k0 += 32) {
    __syncthreads();
    stage_g(Ag + k0, NH, As, t);
    stage_g(Bg + k0, NH, Bs, t);
    __syncthreads();
    MFMA_STEP(As, Bs)
  }
#pragma unroll
  for (int mi = 0; mi < 4; ++mi)
#pragma unroll
    for (int ni = 0; ni < 4; ++ni)
#pragma unroll
      for (int r = 0; r < 4; ++r) {
        int l = l0 + wr + mi * 16 + g * 4 + r;
        int m = m0 + wc + ni * 16 + ln;
        S[((size_t)b * NLC + l) * NLQ + m] =
            acc[mi][ni][r] + s1[b * NLC + l] + s2[b * NLQ + m];
      }
}

// per-row (over m) masked max & inverse-sum-exp. One wave per row.
__global__ __launch_bounds__(256) void k_rowstats(const float* __restrict__ S,
                                                  const int* __restrict__ qmask,
                                                  float* __restrict__ rmax,
                                                  float* __restrict__ rinv) {
  int wave = threadIdx.x >> 6, lane = threadIdx.x & 63;
  int idx = (blockIdx.x << 2) + wave;
  int b = idx >> 10;
  const float* row = S + (size_t)idx * NLQ;
  const int* qm = qmask + b * NLQ;
  float v[4], mx = -INFINITY;
#pragma unroll
  for (int i = 0; i < 4; ++i) {
    int m = lane + (i << 6);
    float x = row[m] + (qm[m] ? 0.f : NEGV);
    v[i] = x;
    mx = fmaxf(mx, x);
  }
#pragma unroll
  for (int off = 32; off > 0; off >>= 1) mx = fmaxf(mx, __shfl_xor(mx, off));
  float sm = 0.f;
#pragma unroll
  for (int i = 0; i < 4; ++i) sm += expf(v[i] - mx);
#pragma unroll
  for (int off = 32; off > 0; off >>= 1) sm += __shfl_xor(sm, off);
  if (lane == 0) {
    rmax[idx] = mx;
    rinv[idx] = 1.0f / sm;
  }
}

// per-column (over l) masked max & sum-exp partials, one 64-row chunk per block.
__global__ __launch_bounds__(256) void k_colpart(const float* __restrict__ S,
                                                 const int* __restrict__ cmask,
                                                 float* __restrict__ pmax,
                                                 float* __restrict__ psum) {
  int idx = blockIdx.x;  // ((b*4 + mb)*LCHUNK + chunk)
  int chunk = idx & (LCHUNK - 1);
  int mb = (idx >> 4) & 3;
  int b = idx >> 6;
  int m0 = mb << 6;
  int tx = threadIdx.x & 63, ty = threadIdx.x >> 6;
  const float* Sb = S + (size_t)b * NLC * NLQ + (size_t)(chunk * 64) * NLQ;
  const int* cm = cmask + b * NLC + chunk * 64;
  float mx = -INFINITY, sm = 0.f;
#pragma unroll 4
  for (int l = ty; l < 64; l += 4) {
    float x = Sb[(size_t)l * NLQ + m0 + tx] + (cm[l] ? 0.f : NEGV);
    float nmx = fmaxf(mx, x);
    sm = sm * expf(mx - nmx) + expf(x - nmx);
    mx = nmx;
  }
  __shared__ float smx[4][64], ssm[4][64];
  smx[ty][tx] = mx;
  ssm[ty][tx] = sm;
  __syncthreads();
  if (ty == 0) {
#pragma unroll
    for (int r = 1; r < 4; ++r) {
      float m2 = smx[r][tx], s2 = ssm[r][tx];
      float nm = fmaxf(mx, m2);
      sm = sm * expf(mx - nm) + s2 * expf(m2 - nm);
      mx = nm;
    }
    int m = (b << 8) + m0 + tx;  // global column id
    pmax[(size_t)m * LCHUNK + chunk] = mx;
    psum[(size_t)m * LCHUNK + chunk] = sm;
  }
}

// combine LCHUNK partials per column -> cmax, cinv. One thread per column.
__global__ __launch_bounds__(256) void k_colfin(const float* __restrict__ pmax,
                                                const float* __restrict__ psum,
                                                float* __restrict__ cmax,
                                                float* __restrict__ cinv) {
  int m = blockIdx.x * 256 + threadIdx.x;  // [0, NB*NLQ)
  const float* pm = pmax + (size_t)m * LCHUNK;
  const float* ps = psum + (size_t)m * LCHUNK;
  float mx = pm[0], sm = ps[0];
#pragma unroll
  for (int c = 1; c < LCHUNK; ++c) {
    float m2 = pm[c], s2 = ps[c];
    float nm = fmaxf(mx, m2);
    sm = sm * expf(mx - nm) + s2 * expf(m2 - nm);
    mx = nm;
  }
  cmax[m] = mx;
  cinv[m] = 1.0f / sm;
}

// ------ Tp[ks][b][h][m] = sum_{l in chunk ks} C[h][l] * S_col[l][m] ------
// split-K partials (f32); M=h, N=m, K=l chunk of 256.
__global__ __launch_bounds__(256) void k_tgemm(
    const float* __restrict__ C, const float* __restrict__ S,
    const int* __restrict__ cmask, const float* __restrict__ cmax,
    const float* __restrict__ cinv, float* __restrict__ Tp) {
  __shared__ short As[4096], Bs[4096];
  int b = blockIdx.z;
  int ks = blockIdx.y;
  int h0 = (blockIdx.x & 1) << 7;
  int m0 = (blockIdx.x >> 1) << 7;
  GEMM_IDS
  const float* Cb = C + ((size_t)b * NH + h0) * NLC;
  const float* Sb = S + (size_t)b * NLC * NLQ;
  const float* cmx = cmax + b * NLQ + m0;
  const float* civ = cinv + b * NLQ + m0;
  const int* cm = cmask + b * NLC;
  f32x4 acc[4][4] = {};
  int kbeg = ks * (NLC / KSPLIT), kend = kbeg + NLC / KSPLIT;
  for (int k0 = kbeg; k0 < kend; k0 += 32) {
    __syncthreads();
    {  // A: reg-convert from f32 C (rows h, K=l minor)
      int c = lane & 3;
#pragma unroll
      for (int i = 0; i < 2; ++i) {
        int seg = w + i * 4, r = seg * 16 + (lane >> 2);
        const float* src = &Cb[(size_t)r * NLC + k0 + c * 8];
        float4 v0 = *(const float4*)src;
        float4 v1 = *(const float4*)(src + 4);
        lds_w8(As, r, c, cvt8(v0, v1));
      }
    }
    {  // B: transposing exp-staging from f32 S (rows m, K=l)
      int lloc = t >> 3, l = k0 + lloc;
      float cmf = (float)cm[l];
      const float* srow = &Sb[(size_t)l * NLQ + m0];
      int g2 = lloc >> 3, kin = lloc & 7;
#pragma unroll
      for (int mi4 = 0; mi4 < 4; ++mi4) {
        int m = ((t & 7) << 2) + (mi4 << 5);
        float4 sv = *(const float4*)&srow[m];
        float p[4];
        p[0] = expf(sv.x - cmx[m + 0]) * civ[m + 0] * cmf;
        p[1] = expf(sv.y - cmx[m + 1]) * civ[m + 1] * cmf;
        p[2] = expf(sv.z - cmx[m + 2]) * civ[m + 2] * cmf;
        p[3] = expf(sv.w - cmx[m + 3]) * civ[m + 3] * cmf;
#pragma unroll
        for (int j = 0; j < 4; ++j) {
          int R = m + j;
          int byteoff =
              (R << 6) + (((g2 ^ ((R >> 1) & 3)) & 3) << 4) + (kin << 1);
          *(short*)((char*)Bs + byteoff) = bf16_of(p[j]);
        }
      }
    }
    __syncthreads();
    MFMA_STEP(As, Bs)
  }
  float* dst = Tp + ((size_t)ks * NB + b) * NH * NLQ;
#pragma unroll
  for (int mi = 0; mi < 4; ++mi)
#pragma unroll
    for (int ni = 0; ni < 4; ++ni)
#pragma unroll
      for (int r = 0; r < 4; ++r) {
        int h = h0 + wr + mi * 16 + g * 4 + r;
        int m = m0 + wc + ni * 16 + ln;
        dst[(size_t)h * NLQ + m] = acc[mi][ni][r];
      }
}

// reduce KSPLIT partials -> bf16 Tt[b][h][m]
__global__ __launch_bounds__(256) void k_tfin(const float* __restrict__ Tp,
                                              short* __restrict__ Tt) {
  size_t i = ((size_t)blockIdx.x * 256 + threadIdx.x) * 4;
  const size_t stride = (size_t)NB * NH * NLQ;
  float4 s = *(const float4*)&Tp[i];
#pragma unroll
  for (int ks = 1; ks < KSPLIT; ++ks) {
    float4 v = *(const float4*)&Tp[i + ks * stride];
    s.x += v.x; s.y += v.y; s.z += v.z; s.w += v.w;
  }
  short4 o;
  o.x = bf16_of(s.x);
  o.y = bf16_of(s.y);
  o.z = bf16_of(s.z);
  o.w = bf16_of(s.w);
  *(short4*)&Tt[i] = o;
}

// -------- [A|Bv][l][h] = sum_m S_row[l][m] * X[h][m]  (M=l, N=h', K=m) --------
__global__ __launch_bounds__(256) void k_abgemm(
    const float* __restrict__ S, const float* __restrict__ Q,
    const short* __restrict__ Tt, const int* __restrict__ qmask,
    const float* __restrict__ rmax, const float* __restrict__ rinv,
    short* __restrict__ A_lh, short* __restrict__ Bv_lh) {
  __shared__ short As[4096], Bs[4096];
  int b = blockIdx.z, l0 = blockIdx.y << 7, nb = blockIdx.x;
  GEMM_IDS
  const float* Sb = S + ((size_t)b * NLC + l0) * NLQ;
  f32x4 acc[4][4] = {};
  for (int k0 = 0; k0 < NLQ; k0 += 32) {
    __syncthreads();
    {  // A: on-the-fly S_row from f32 S (rows l, K=m minor)
      int c = lane & 3;
      const int* qm = qmask + b * NLQ + k0 + c * 8;
#pragma unroll
      for (int i = 0; i < 2; ++i) {
        int seg = w + i * 4, r = seg * 16 + (lane >> 2);
        int l = l0 + r;
        const float* src = &Sb[(size_t)r * NLQ + k0 + c * 8];
        float4 v0 = *(const float4*)src;
        float4 v1 = *(const float4*)(src + 4);
        float mx = rmax[b * NLC + l], iv = rinv[b * NLC + l];
        short8 o;
        o[0] = bf16_of(expf(v0.x - mx) * iv * (float)qm[0]);
        o[1] = bf16_of(expf(v0.y - mx) * iv * (float)qm[1]);
        o[2] = bf16_of(expf(v0.z - mx) * iv * (float)qm[2]);
        o[3] = bf16_of(expf(v0.w - mx) * iv * (float)qm[3]);
        o[4] = bf16_of(expf(v1.x - mx) * iv * (float)qm[4]);
        o[5] = bf16_of(expf(v1.y - mx) * iv * (float)qm[5]);
        o[6] = bf16_of(expf(v1.z - mx) * iv * (float)qm[6]);
        o[7] = bf16_of(expf(v1.w - mx) * iv * (float)qm[7]);
        lds_w8(As, r, c, o);
      }
    }
    if (nb < 2) {  // B: reg-convert f32 Q (rows h, K=m minor)
      const float* Qb = Q + ((size_t)b * NH + nb * 128) * NLQ;
      int c = lane & 3;
#pragma unroll
      for (int i = 0; i < 2; ++i) {
        int seg = w + i * 4, r = seg * 16 + (lane >> 2);
        const float* src = &Qb[(size_t)r * NLQ + k0 + c * 8];
        float4 v0 = *(const float4*)src;
        float4 v1 = *(const float4*)(src + 4);
        lds_w8(Bs, r, c, cvt8(v0, v1));
      }
    } else {  // B: bf16 Tt via global_load_lds
      const short* Tb = Tt + ((size_t)b * NH + (nb - 2) * 128) * NLQ;
      stage_g(Tb + k0, NLQ, Bs, t);
    }
    __syncthreads();
    MFMA_STEP(As, Bs)
  }
  short* dst = (nb & 2) ? Bv_lh : A_lh;
  int hbase = (nb & 1) << 7;
#pragma unroll
  for (int mi = 0; mi < 4; ++mi)
#pragma unroll
    for (int ni = 0; ni < 4; ++ni)
#pragma unroll
      for (int r = 0; r < 4; ++r) {
        int l = l0 + wr + mi * 16 + g * 4 + r;
        int h = hbase + wc + ni * 16 + ln;
        dst[((size_t)b * NLC + l) * NH + h] = bf16_of(acc[mi][ni][r]);
      }
}

// -------- out[h][l] = relu(b + sum_f W[h][f]*cat[l][f])  (M=h, N=l, K=f) ------
__global__ __launch_bounds__(256) void k_out(
    const float* __restrict__ W, const short* __restrict__ Ct_lh,
    const short* __restrict__ A_lh, const short* __restrict__ Bv_lh,
    const float* __restrict__ br, float* __restrict__ out) {
  __shared__ short As[4096], Bs[4096];
  int b = blockIdx.z, h0 = blockIdx.y << 7, l0 = blockIdx.x << 7;
  GEMM_IDS
  f32x4 acc[4][4] = {};
  for (int k0 = 0; k0 < 4 * NH; k0 += 32) {
    __syncthreads();
    {  // A: reg-convert from f32 W (rows h, K=f minor)
      int c = lane & 3;
#pragma unroll
      for (int i = 0; i < 2; ++i) {
        int seg = w + i * 4, r = seg * 16 + (lane >> 2);
        const float* src = &W[(size_t)(h0 + r) * (4 * NH) + k0 + c * 8];
        float4 v0 = *(const float4*)src;
        float4 v1 = *(const float4*)(src + 4);
        lds_w8(As, r, c, cvt8(v0, v1));
      }
    }
    int reg = k0 >> 8, ko = k0 & 255;
    if (reg < 2) {  // B: Ct or A directly via global_load_lds
      const short* base = (reg == 0) ? Ct_lh : A_lh;
      stage_g(base + ((size_t)b * NLC + l0) * NH + ko, NH, Bs, t);
    } else {  // B: elementwise Ct * (A or Bv), reg-staged
      const short* base = (reg == 2) ? A_lh : Bv_lh;
      int c = lane & 3;
#pragma unroll
      for (int i = 0; i < 2; ++i) {
        int seg = w + i * 4, r = seg * 16 + (lane >> 2);
        size_t off = ((size_t)b * NLC + l0 + r) * NH + ko + c * 8;
        short8 x1 = *(const short8*)&Ct_lh[off];
        short8 x2 = *(const short8*)&base[off];
        short8 o;
#pragma unroll
        for (int j = 0; j < 8; ++j) o[j] = bf16_of(f_of(x1[j]) * f_of(x2[j]));
        lds_w8(Bs, r, c, o);
      }
    }
    __syncthreads();
    MFMA_STEP(As, Bs)
  }
#pragma unroll
  for (int mi = 0; mi < 4; ++mi)
#pragma unroll
    for (int ni = 0; ni < 4; ++ni) {
      int h = h0 + wr + mi * 16 + g * 4;
      int l = l0 + wc + ni * 16 + ln;
#pragma unroll
      for (int r = 0; r < 4; ++r) {
        float bias = br[h + r];
        out[((size_t)b * NH + h + r) * NLC + l] =
            fmaxf(acc[mi][ni][r] + bias, 0.f);
      }
    }
}

extern "C" void kernel_launch(void* const* d_in, const int* in_sizes, int n_in,
                              void* d_out, int out_size, void* d_ws,
                              size_t ws_size, hipStream_t stream) {
  (void)in_sizes;
  (void)n_in;
  (void)out_size;
  (void)ws_size;
  const float* C = (const float*)d_in[0];
  const float* Q = (const float*)d_in[1];
  const int* cmask = (const int*)d_in[2];
  const int* qmask = (const int*)d_in[3];
  const float* w = (const float*)d_in[4];
  const float* W = (const float*)d_in[5];
  const float* br = (const float*)d_in[6];
  float* out = (float*)d_out;

  char* p = (char*)d_ws;
  float* S = (float*)p;      p += (size_t)NB * NLC * NLQ * 4;   // 33.6 MB
  short* Ct_lh = (short*)p;  p += (size_t)NB * NLC * NH * 2;    // 16.8 MB
  short* A_lh = (short*)p;   p += (size_t)NB * NLC * NH * 2;    // 16.8 MB
  short* Bv_lh = (short*)p;  p += (size_t)NB * NLC * NH * 2;    // 16.8 MB
  short* Tt = (short*)p;     p += (size_t)NB * NH * NLQ * 2;    // 4.2 MB
  short* Qtw3 = (short*)p;   p += (size_t)NB * NLQ * NH * 2;    // 4.2 MB
  float* s1 = (float*)p;     p += (size_t)NB * NLC * 4;
  float* s2 = (float*)p;     p += (size_t)NB * NLQ * 4;
  float* rmax = (float*)p;   p += (size_t)NB * NLC * 4;
  float* rinv = (float*)p;   p += (size_t)NB * NLC * 4;
  float* cmax = (float*)p;   p += (size_t)NB * NLQ * 4;
  float* cinv = (float*)p;   p += (size_t)NB * NLQ * 4;
  float* pmax = (float*)p;   p += (size_t)NB * NLQ * LCHUNK * 4;
  float* psum = (float*)p;   p += (size_t)NB * NLQ * LCHUNK * 4;
  // tgemm split-K partials: reuse A_lh+Bv_lh (33.6 MB, dead until k_abgemm).
  float* Tp = (float*)A_lh;  // KSPLIT * NB*NH*NLQ * 4 = 33.6 MB exactly

  k_prep_c<<<dim3(NLC / 64, NH / 64, NB), dim3(256), 0, stream>>>(C, Ct_lh);
  k_prep_q<<<dim3(NLQ / 64, NH / 64, NB), dim3(256), 0, stream>>>(Q, w, Qtw3);
  k_s1<<<dim3(NB * (NLC / 256)), dim3(256), 0, stream>>>(C, w, s1);
  k_s2<<<dim3(NB), dim3(256), 0, stream>>>(Q, w, s2);
  k_sgemm<<<dim3(NLQ / 128, NLC / 128, NB), dim3(256), 0, stream>>>(
      Ct_lh, Qtw3, s1, s2, S);
  k_rowstats<<<dim3(NB * NLC / 4), dim3(256), 0, stream>>>(S, qmask, rmax,
                                                           rinv);
  k_colpart<<<dim3(NB * 4 * LCHUNK), dim3(256), 0, stream>>>(S, cmask, pmax,
                                                             psum);
  k_colfin<<<dim3(NB * NLQ / 256), dim3(256), 0, stream>>>(pmax, psum, cmax,
                                                           cinv);
  k_tgemm<<<dim3(4, KSPLIT, NB), dim3(256), 0, stream>>>(C, S, cmask, cmax,
                                                         cinv, Tp);
  k_tfin<<<dim3(NB * NH * NLQ / 1024), dim3(256), 0, stream>>>(Tp, Tt);
  k_abgemm<<<dim3(4, NLC / 128, NB), dim3(256), 0, stream>>>(
      S, Q, Tt, qmask, rmax, rinv, A_lh, Bv_lh);
  k_out<<<dim3(NLC / 128, NH / 128, NB), dim3(256), 0, stream>>>(
      W, Ct_lh, A_lh, Bv_lh, br, out);
}

// Round 5
// 189.335 us; speedup vs baseline: 3.4915x; 1.0226x over previous
//
#include <hip/hip_runtime.h>
#include <math.h>

#define NB 32
#define NH 256
#define NLC 1024
#define NLQ 256
#define NEGV (-1e30f)
#define LCHUNK 16  // column-stats l-chunks (each 64 rows)
#define KSPLIT 4   // tgemm split-K factor

typedef short short8 __attribute__((ext_vector_type(8)));
typedef float f32x4 __attribute__((ext_vector_type(4)));

__device__ inline short bf16_of(float f) {
  union { float f; unsigned u; } v;
  v.f = f;
  unsigned r = (v.u + 0x7fffu + ((v.u >> 16) & 1u)) >> 16;
  return (short)r;
}
__device__ inline float f_of(short s) {
  union { unsigned u; float f; } v;
  v.u = ((unsigned)(unsigned short)s) << 16;
  return v.f;
}
__device__ inline short8 cvt8(float4 a, float4 b) {
  short8 o;
  o[0] = bf16_of(a.x); o[1] = bf16_of(a.y); o[2] = bf16_of(a.z); o[3] = bf16_of(a.w);
  o[4] = bf16_of(b.x); o[5] = bf16_of(b.y); o[6] = bf16_of(b.z); o[7] = bf16_of(b.w);
  return o;
}

// ---- swizzled 128x32 bf16 LDS tile helpers (row = 64B, slot ^= (row>>1)&3) ----
__device__ inline void lds_w8(short* lds, int r, int c, short8 v) {
  int byteoff = (r << 6) + (((c ^ ((r >> 1) & 3)) & 3) << 4);
  *(short8*)((char*)lds + byteoff) = v;
}
__device__ inline short8 lds_r8(const short* lds, int R, int g) {
  int byteoff = (R << 6) + (((g ^ ((R >> 1) & 3)) & 3) << 4);
  return *(const short8*)((const char*)lds + byteoff);
}
// global_load_lds staging of a 128x32 bf16 tile from K-minor src (ld elements).
// Source group pre-permuted per-lane so linear LDS bytes match swizzled reads.
__device__ inline void stage_g(const short* src, int ld, short* lds, int t) {
  int L = t & 63, w = t >> 6;
  int cp = (L & 3) ^ ((L >> 3) & 3);
#pragma unroll
  for (int i = 0; i < 2; ++i) {
    int seg = w + i * 4;
    const short* g = src + (size_t)(seg * 16 + (L >> 2)) * ld + cp * 8;
    __builtin_amdgcn_global_load_lds(
        (const __attribute__((address_space(1))) unsigned int*)g,
        (__attribute__((address_space(3))) unsigned int*)(lds + seg * 512), 16,
        0, 0);
  }
}

#define GEMM_IDS                                       \
  int t = threadIdx.x, lane = t & 63, w = t >> 6;      \
  int ln = lane & 15, g = lane >> 4;                   \
  int wr = (w >> 1) << 6, wc = (w & 1) << 6;           \
  (void)wr; (void)wc;

#define MFMA_STEP(AS, BS)                                                      \
  {                                                                            \
    short8 af[4], bfr[4];                                                      \
    _Pragma("unroll") for (int mi = 0; mi < 4; ++mi) af[mi] =                  \
        lds_r8(AS, wr + mi * 16 + ln, g);                                      \
    _Pragma("unroll") for (int ni = 0; ni < 4; ++ni) bfr[ni] =                 \
        lds_r8(BS, wc + ni * 16 + ln, g);                                      \
    _Pragma("unroll") for (int mi = 0; mi < 4; ++mi)                           \
        _Pragma("unroll") for (int ni = 0; ni < 4; ++ni) acc[mi][ni] =         \
            __builtin_amdgcn_mfma_f32_16x16x32_bf16(af[mi], bfr[ni],           \
                                                    acc[mi][ni], 0, 0, 0);     \
  }

// ---------------- prep: Ct_lh[l][h] = bf16(C[h][l]) ----------------
__global__ __launch_bounds__(256) void k_prep_c(const float* __restrict__ C,
                                                short* __restrict__ Ct_lh) {
  __shared__ float Ts[64][65];
  int b = blockIdx.z, h0 = blockIdx.y << 6, l0 = blockIdx.x << 6;
  int t = threadIdx.x;
  int hr = t >> 4, lc = (t & 15) << 2;
  const float* Cb = C + ((size_t)b * NH + h0) * NLC + l0;
#pragma unroll
  for (int i = 0; i < 4; ++i) {
    float4 v = *(const float4*)&Cb[(size_t)(hr + i * 16) * NLC + lc];
    Ts[hr + i * 16][lc + 0] = v.x;
    Ts[hr + i * 16][lc + 1] = v.y;
    Ts[hr + i * 16][lc + 2] = v.z;
    Ts[hr + i * 16][lc + 3] = v.w;
  }
  __syncthreads();
  int lr = t >> 2, hc = (t & 3) << 4;
  short* dst = &Ct_lh[((size_t)b * NLC + l0 + lr) * NH + h0 + hc];
  short8 o0, o1;
#pragma unroll
  for (int j = 0; j < 8; ++j) o0[j] = bf16_of(Ts[hc + j][lr]);
#pragma unroll
  for (int j = 0; j < 8; ++j) o1[j] = bf16_of(Ts[hc + 8 + j][lr]);
  *(short8*)dst = o0;
  *(short8*)(dst + 8) = o1;
}

// ---------------- prep: Qtw3[m][h] = bf16(Q[h][m]*w3[h]) ----------------
__global__ __launch_bounds__(256) void k_prep_q(const float* __restrict__ Q,
                                                const float* __restrict__ w,
                                                short* __restrict__ Qtw3) {
  __shared__ float Ts[64][65];
  int b = blockIdx.z, h0 = blockIdx.y << 6, m0 = blockIdx.x << 6;
  int t = threadIdx.x;
  int hr = t >> 4, mc = (t & 15) << 2;
  const float* w3 = w + 2 * NH;
  const float* Qb = Q + ((size_t)b * NH + h0) * NLQ + m0;
#pragma unroll
  for (int i = 0; i < 4; ++i) {
    int h = hr + i * 16;
    float w3v = w3[h0 + h];
    float4 v = *(const float4*)&Qb[(size_t)h * NLQ + mc];
    Ts[h][mc + 0] = v.x * w3v;
    Ts[h][mc + 1] = v.y * w3v;
    Ts[h][mc + 2] = v.z * w3v;
    Ts[h][mc + 3] = v.w * w3v;
  }
  __syncthreads();
  int mr = t >> 2, hc = (t & 3) << 4;
  short* dst = &Qtw3[((size_t)b * NLQ + m0 + mr) * NH + h0 + hc];
  short8 o0, o1;
#pragma unroll
  for (int j = 0; j < 8; ++j) o0[j] = bf16_of(Ts[hc + j][mr]);
#pragma unroll
  for (int j = 0; j < 8; ++j) o1[j] = bf16_of(Ts[hc + 8 + j][mr]);
  *(short8*)dst = o0;
  *(short8*)(dst + 8) = o1;
}

// ---------------- prep: plain f32 -> bf16 copies ----------------
__global__ __launch_bounds__(256) void k_prep_bf16(const float* __restrict__ X,
                                                   short* __restrict__ Y) {
  size_t i = ((size_t)blockIdx.x * 256 + threadIdx.x) * 8;
  float4 v0 = *(const float4*)&X[i];
  float4 v1 = *(const float4*)&X[i + 4];
  *(short8*)&Y[i] = cvt8(v0, v1);
}

// s1[b][l] = sum_h C[b][h][l] * w1[h]
__global__ __launch_bounds__(256) void k_s1(const float* __restrict__ C,
                                            const float* __restrict__ w,
                                            float* __restrict__ s1) {
  int b = blockIdx.x >> 2;
  int l = ((blockIdx.x & 3) << 8) + threadIdx.x;
  const float* Cb = C + (size_t)b * NH * NLC;
  float acc = 0.f;
#pragma unroll 8
  for (int h = 0; h < NH; ++h) acc += Cb[(size_t)h * NLC + l] * w[h];
  s1[b * NLC + l] = acc;
}

// s2[b][m] = sum_h Q[b][h][m] * w2[h]
__global__ __launch_bounds__(256) void k_s2(const float* __restrict__ Q,
                                            const float* __restrict__ w,
                                            float* __restrict__ s2) {
  int b = blockIdx.x;
  int m = threadIdx.x;
  const float* Qb = Q + (size_t)b * NH * NLQ;
  const float* w2 = w + NH;
  float acc = 0.f;
#pragma unroll 8
  for (int h = 0; h < NH; ++h) acc += Qb[(size_t)h * NLQ + m] * w2[h];
  s2[b * NLQ + m] = acc;
}

// ---------------- S = Ct_lh @ Qtw3^T + s1 + s2  (M=l, N=m, K=h) ----------------
__global__ __launch_bounds__(256) void k_sgemm(
    const short* __restrict__ Ct_lh, const short* __restrict__ Qtw3,
    const float* __restrict__ s1, const float* __restrict__ s2,
    float* __restrict__ S) {
  __shared__ short As[4096], Bs[4096];
  int b = blockIdx.z, l0 = blockIdx.y << 7, m0 = blockIdx.x << 7;
  GEMM_IDS
  const short* Ag = Ct_lh + ((size_t)b * NLC + l0) * NH;
  const short* Bg = Qtw3 + ((size_t)b * NLQ + m0) * NH;
  f32x4 acc[4][4] = {};
  for (int k0 = 0; k0 < NH; k0 += 32) {
    __syncthreads();
    stage_g(Ag + k0, NH, As, t);
    stage_g(Bg + k0, NH, Bs, t);
    __syncthreads();
    MFMA_STEP(As, Bs)
  }
#pragma unroll
  for (int mi = 0; mi < 4; ++mi)
#pragma unroll
    for (int ni = 0; ni < 4; ++ni)
#pragma unroll
      for (int r = 0; r < 4; ++r) {
        int l = l0 + wr + mi * 16 + g * 4 + r;
        int m = m0 + wc + ni * 16 + ln;
        S[((size_t)b * NLC + l) * NLQ + m] =
            acc[mi][ni][r] + s1[b * NLC + l] + s2[b * NLQ + m];
      }
}

// per-row (over m) masked max & inverse-sum-exp. One wave per row.
__global__ __launch_bounds__(256) void k_rowstats(const float* __restrict__ S,
                                                  const int* __restrict__ qmask,
                                                  float* __restrict__ rmax,
                                                  float* __restrict__ rinv) {
  int wave = threadIdx.x >> 6, lane = threadIdx.x & 63;
  int idx = (blockIdx.x << 2) + wave;
  int b = idx >> 10;
  const float* row = S + (size_t)idx * NLQ;
  const int* qm = qmask + b * NLQ;
  float v[4], mx = -INFINITY;
#pragma unroll
  for (int i = 0; i < 4; ++i) {
    int m = lane + (i << 6);
    float x = row[m] + (qm[m] ? 0.f : NEGV);
    v[i] = x;
    mx = fmaxf(mx, x);
  }
#pragma unroll
  for (int off = 32; off > 0; off >>= 1) mx = fmaxf(mx, __shfl_xor(mx, off));
  float sm = 0.f;
#pragma unroll
  for (int i = 0; i < 4; ++i) sm += expf(v[i] - mx);
#pragma unroll
  for (int off = 32; off > 0; off >>= 1) sm += __shfl_xor(sm, off);
  if (lane == 0) {
    rmax[idx] = mx;
    rinv[idx] = 1.0f / sm;
  }
}

// per-column (over l) masked max & sum-exp partials, one 64-row chunk per block.
__global__ __launch_bounds__(256) void k_colpart(const float* __restrict__ S,
                                                 const int* __restrict__ cmask,
                                                 float* __restrict__ pmax,
                                                 float* __restrict__ psum) {
  int idx = blockIdx.x;  // ((b*4 + mb)*LCHUNK + chunk)
  int chunk = idx & (LCHUNK - 1);
  int mb = (idx >> 4) & 3;
  int b = idx >> 6;
  int m0 = mb << 6;
  int tx = threadIdx.x & 63, ty = threadIdx.x >> 6;
  const float* Sb = S + (size_t)b * NLC * NLQ + (size_t)(chunk * 64) * NLQ;
  const int* cm = cmask + b * NLC + chunk * 64;
  float mx = -INFINITY, sm = 0.f;
#pragma unroll 4
  for (int l = ty; l < 64; l += 4) {
    float x = Sb[(size_t)l * NLQ + m0 + tx] + (cm[l] ? 0.f : NEGV);
    float nmx = fmaxf(mx, x);
    sm = sm * expf(mx - nmx) + expf(x - nmx);
    mx = nmx;
  }
  __shared__ float smx[4][64], ssm[4][64];
  smx[ty][tx] = mx;
  ssm[ty][tx] = sm;
  __syncthreads();
  if (ty == 0) {
#pragma unroll
    for (int r = 1; r < 4; ++r) {
      float m2 = smx[r][tx], s2 = ssm[r][tx];
      float nm = fmaxf(mx, m2);
      sm = sm * expf(mx - nm) + s2 * expf(m2 - nm);
      mx = nm;
    }
    int m = (b << 8) + m0 + tx;  // global column id
    pmax[(size_t)m * LCHUNK + chunk] = mx;
    psum[(size_t)m * LCHUNK + chunk] = sm;
  }
}

// combine LCHUNK partials per column -> cmax, cinv. One thread per column.
__global__ __launch_bounds__(256) void k_colfin(const float* __restrict__ pmax,
                                                const float* __restrict__ psum,
                                                float* __restrict__ cmax,
                                                float* __restrict__ cinv) {
  int m = blockIdx.x * 256 + threadIdx.x;  // [0, NB*NLQ)
  const float* pm = pmax + (size_t)m * LCHUNK;
  const float* ps = psum + (size_t)m * LCHUNK;
  float mx = pm[0], sm = ps[0];
#pragma unroll
  for (int c = 1; c < LCHUNK; ++c) {
    float m2 = pm[c], s2 = ps[c];
    float nm = fmaxf(mx, m2);
    sm = sm * expf(mx - nm) + s2 * expf(m2 - nm);
    mx = nm;
  }
  cmax[m] = mx;
  cinv[m] = 1.0f / sm;
}

// ------ Tp[ks][b][h][m] = sum_{l in chunk ks} C[h][l] * S_col[l][m] ------
// split-K partials (f32); M=h, N=m, K=l chunk of 256.
__global__ __launch_bounds__(256) void k_tgemm(
    const float* __restrict__ C, const float* __restrict__ S,
    const int* __restrict__ cmask, const float* __restrict__ cmax,
    const float* __restrict__ cinv, float* __restrict__ Tp) {
  __shared__ short As[4096], Bs[4096];
  int b = blockIdx.z;
  int ks = blockIdx.y;
  int h0 = (blockIdx.x & 1) << 7;
  int m0 = (blockIdx.x >> 1) << 7;
  GEMM_IDS
  const float* Cb = C + ((size_t)b * NH + h0) * NLC;
  const float* Sb = S + (size_t)b * NLC * NLQ;
  const float* cmx = cmax + b * NLQ + m0;
  const float* civ = cinv + b * NLQ + m0;
  const int* cm = cmask + b * NLC;
  f32x4 acc[4][4] = {};
  int kbeg = ks * (NLC / KSPLIT), kend = kbeg + NLC / KSPLIT;
  for (int k0 = kbeg; k0 < kend; k0 += 32) {
    __syncthreads();
    {  // A: reg-convert from f32 C (rows h, K=l minor)
      int c = lane & 3;
#pragma unroll
      for (int i = 0; i < 2; ++i) {
        int seg = w + i * 4, r = seg * 16 + (lane >> 2);
        const float* src = &Cb[(size_t)r * NLC + k0 + c * 8];
        float4 v0 = *(const float4*)src;
        float4 v1 = *(const float4*)(src + 4);
        lds_w8(As, r, c, cvt8(v0, v1));
      }
    }
    {  // B: transposing exp-staging from f32 S (rows m, K=l)
      int lloc = t >> 3, l = k0 + lloc;
      float cmf = (float)cm[l];
      const float* srow = &Sb[(size_t)l * NLQ + m0];
      int g2 = lloc >> 3, kin = lloc & 7;
#pragma unroll
      for (int mi4 = 0; mi4 < 4; ++mi4) {
        int m = ((t & 7) << 2) + (mi4 << 5);
        float4 sv = *(const float4*)&srow[m];
        float p[4];
        p[0] = expf(sv.x - cmx[m + 0]) * civ[m + 0] * cmf;
        p[1] = expf(sv.y - cmx[m + 1]) * civ[m + 1] * cmf;
        p[2] = expf(sv.z - cmx[m + 2]) * civ[m + 2] * cmf;
        p[3] = expf(sv.w - cmx[m + 3]) * civ[m + 3] * cmf;
#pragma unroll
        for (int j = 0; j < 4; ++j) {
          int R = m + j;
          int byteoff =
              (R << 6) + (((g2 ^ ((R >> 1) & 3)) & 3) << 4) + (kin << 1);
          *(short*)((char*)Bs + byteoff) = bf16_of(p[j]);
        }
      }
    }
    __syncthreads();
    MFMA_STEP(As, Bs)
  }
  float* dst = Tp + ((size_t)ks * NB + b) * NH * NLQ;
#pragma unroll
  for (int mi = 0; mi < 4; ++mi)
#pragma unroll
    for (int ni = 0; ni < 4; ++ni)
#pragma unroll
      for (int r = 0; r < 4; ++r) {
        int h = h0 + wr + mi * 16 + g * 4 + r;
        int m = m0 + wc + ni * 16 + ln;
        dst[(size_t)h * NLQ + m] = acc[mi][ni][r];
      }
}

// reduce KSPLIT partials -> bf16 Tt[b][h][m]
__global__ __launch_bounds__(256) void k_tfin(const float* __restrict__ Tp,
                                              short* __restrict__ Tt) {
  size_t i = ((size_t)blockIdx.x * 256 + threadIdx.x) * 4;
  const size_t stride = (size_t)NB * NH * NLQ;
  float4 s = *(const float4*)&Tp[i];
#pragma unroll
  for (int ks = 1; ks < KSPLIT; ++ks) {
    float4 v = *(const float4*)&Tp[i + ks * stride];
    s.x += v.x; s.y += v.y; s.z += v.z; s.w += v.w;
  }
  short4 o;
  o.x = bf16_of(s.x);
  o.y = bf16_of(s.y);
  o.z = bf16_of(s.z);
  o.w = bf16_of(s.w);
  *(short4*)&Tt[i] = o;
}

// ---- [A | Ct*Bv][l][h] = f(sum_m S_row[l][m] * X[h][m])  (M=l, N=h', K=m) ----
// nb<2: X = Qb (bf16 Q), writes A_lh. nb>=2: X = Tt, writes CtBv_lh = Ct*acc.
__global__ __launch_bounds__(256) void k_abgemm(
    const float* __restrict__ S, const short* __restrict__ Qb_hm,
    const short* __restrict__ Tt, const short* __restrict__ Ct_lh,
    const int* __restrict__ qmask, const float* __restrict__ rmax,
    const float* __restrict__ rinv, short* __restrict__ A_lh,
    short* __restrict__ CtBv_lh) {
  __shared__ short As[4096], Bs[4096];
  int b = blockIdx.z, l0 = blockIdx.y << 7, nb = blockIdx.x;
  GEMM_IDS
  const float* Sb = S + ((size_t)b * NLC + l0) * NLQ;
  const short* Bbase = (nb < 2)
                           ? Qb_hm + ((size_t)b * NH + nb * 128) * NLQ
                           : Tt + ((size_t)b * NH + (nb - 2) * 128) * NLQ;
  f32x4 acc[4][4] = {};
  for (int k0 = 0; k0 < NLQ; k0 += 32) {
    __syncthreads();
    {  // A: on-the-fly S_row from f32 S (rows l, K=m minor)
      int c = lane & 3;
      const int* qm = qmask + b * NLQ + k0 + c * 8;
#pragma unroll
      for (int i = 0; i < 2; ++i) {
        int seg = w + i * 4, r = seg * 16 + (lane >> 2);
        int l = l0 + r;
        const float* src = &Sb[(size_t)r * NLQ + k0 + c * 8];
        float4 v0 = *(const float4*)src;
        float4 v1 = *(const float4*)(src + 4);
        float mx = rmax[b * NLC + l], iv = rinv[b * NLC + l];
        short8 o;
        o[0] = bf16_of(expf(v0.x - mx) * iv * (float)qm[0]);
        o[1] = bf16_of(expf(v0.y - mx) * iv * (float)qm[1]);
        o[2] = bf16_of(expf(v0.z - mx) * iv * (float)qm[2]);
        o[3] = bf16_of(expf(v0.w - mx) * iv * (float)qm[3]);
        o[4] = bf16_of(expf(v1.x - mx) * iv * (float)qm[4]);
        o[5] = bf16_of(expf(v1.y - mx) * iv * (float)qm[5]);
        o[6] = bf16_of(expf(v1.z - mx) * iv * (float)qm[6]);
        o[7] = bf16_of(expf(v1.w - mx) * iv * (float)qm[7]);
        lds_w8(As, r, c, o);
      }
    }
    stage_g(Bbase + k0, NLQ, Bs, t);
    __syncthreads();
    MFMA_STEP(As, Bs)
  }
  int hbase = (nb & 1) << 7;
  if (nb < 2) {
#pragma unroll
    for (int mi = 0; mi < 4; ++mi)
#pragma unroll
      for (int ni = 0; ni < 4; ++ni)
#pragma unroll
        for (int r = 0; r < 4; ++r) {
          int l = l0 + wr + mi * 16 + g * 4 + r;
          int h = hbase + wc + ni * 16 + ln;
          A_lh[((size_t)b * NLC + l) * NH + h] = bf16_of(acc[mi][ni][r]);
        }
  } else {
#pragma unroll
    for (int mi = 0; mi < 4; ++mi)
#pragma unroll
      for (int ni = 0; ni < 4; ++ni)
#pragma unroll
        for (int r = 0; r < 4; ++r) {
          int l = l0 + wr + mi * 16 + g * 4 + r;
          int h = hbase + wc + ni * 16 + ln;
          size_t off = ((size_t)b * NLC + l) * NH + h;
          CtBv_lh[off] = bf16_of(f_of(Ct_lh[off]) * acc[mi][ni][r]);
        }
  }
}

// -------- out[h][l] = relu(b + sum_f W[h][f]*cat[l][f])  (M=h, N=l, K=f) ------
// cat regions along f: [Ct | A | Ct*A | Ct*Bv]; Wb is bf16 W_res.
__global__ __launch_bounds__(256) void k_out(
    const short* __restrict__ Wb, const short* __restrict__ Ct_lh,
    const short* __restrict__ A_lh, const short* __restrict__ CtBv_lh,
    const float* __restrict__ br, float* __restrict__ out) {
  __shared__ short As[4096], Bs[4096];
  int b = blockIdx.z, h0 = blockIdx.y << 7, l0 = blockIdx.x << 7;
  GEMM_IDS
  f32x4 acc[4][4] = {};
  for (int k0 = 0; k0 < 4 * NH; k0 += 32) {
    __syncthreads();
    // A: bf16 W via global_load_lds (rows h, K=f minor, ld=4*NH)
    stage_g(Wb + (size_t)h0 * (4 * NH) + k0, 4 * NH, As, t);
    int reg = k0 >> 8, ko = k0 & 255;
    if (reg != 2) {  // B: Ct, A, or CtBv directly via global_load_lds
      const short* base = (reg == 0) ? Ct_lh : (reg == 1) ? A_lh : CtBv_lh;
      stage_g(base + ((size_t)b * NLC + l0) * NH + ko, NH, Bs, t);
    } else {  // B: elementwise Ct * A, reg-staged
      int c = lane & 3;
#pragma unroll
      for (int i = 0; i < 2; ++i) {
        int seg = w + i * 4, r = seg * 16 + (lane >> 2);
        size_t off = ((size_t)b * NLC + l0 + r) * NH + ko + c * 8;
        short8 x1 = *(const short8*)&Ct_lh[off];
        short8 x2 = *(const short8*)&A_lh[off];
        short8 o;
#pragma unroll
        for (int j = 0; j < 8; ++j) o[j] = bf16_of(f_of(x1[j]) * f_of(x2[j]));
        lds_w8(Bs, r, c, o);
      }
    }
    __syncthreads();
    MFMA_STEP(As, Bs)
  }
#pragma unroll
  for (int mi = 0; mi < 4; ++mi)
#pragma unroll
    for (int ni = 0; ni < 4; ++ni) {
      int h = h0 + wr + mi * 16 + g * 4;
      int l = l0 + wc + ni * 16 + ln;
#pragma unroll
      for (int r = 0; r < 4; ++r) {
        float bias = br[h + r];
        out[((size_t)b * NH + h + r) * NLC + l] =
            fmaxf(acc[mi][ni][r] + bias, 0.f);
      }
    }
}

extern "C" void kernel_launch(void* const* d_in, const int* in_sizes, int n_in,
                              void* d_out, int out_size, void* d_ws,
                              size_t ws_size, hipStream_t stream) {
  (void)in_sizes;
  (void)n_in;
  (void)out_size;
  (void)ws_size;
  const float* C = (const float*)d_in[0];
  const float* Q = (const float*)d_in[1];
  const int* cmask = (const int*)d_in[2];
  const int* qmask = (const int*)d_in[3];
  const float* w = (const float*)d_in[4];
  const float* W = (const float*)d_in[5];
  const float* br = (const float*)d_in[6];
  float* out = (float*)d_out;

  char* p = (char*)d_ws;
  float* S = (float*)p;       p += (size_t)NB * NLC * NLQ * 4;   // 33.6 MB
  short* Ct_lh = (short*)p;   p += (size_t)NB * NLC * NH * 2;    // 16.8 MB
  short* A_lh = (short*)p;    p += (size_t)NB * NLC * NH * 2;    // 16.8 MB
  short* CtBv_lh = (short*)p; p += (size_t)NB * NLC * NH * 2;    // 16.8 MB
  short* Tt = (short*)p;      p += (size_t)NB * NH * NLQ * 2;    // 4.2 MB
  short* Qtw3 = (short*)p;    p += (size_t)NB * NLQ * NH * 2;    // 4.2 MB
  short* Qb_hm = (short*)p;   p += (size_t)NB * NH * NLQ * 2;    // 4.2 MB
  short* Wb = (short*)p;      p += (size_t)NH * 4 * NH * 2;      // 0.5 MB
  float* s1 = (float*)p;      p += (size_t)NB * NLC * 4;
  float* s2 = (float*)p;      p += (size_t)NB * NLQ * 4;
  float* rmax = (float*)p;    p += (size_t)NB * NLC * 4;
  float* rinv = (float*)p;    p += (size_t)NB * NLC * 4;
  float* cmax = (float*)p;    p += (size_t)NB * NLQ * 4;
  float* cinv = (float*)p;    p += (size_t)NB * NLQ * 4;
  float* pmax = (float*)p;    p += (size_t)NB * NLQ * LCHUNK * 4;
  float* psum = (float*)p;    p += (size_t)NB * NLQ * LCHUNK * 4;
  // tgemm split-K partials: reuse A_lh+CtBv_lh (33.6 MB, dead until abgemm).
  float* Tp = (float*)A_lh;

  k_prep_c<<<dim3(NLC / 64, NH / 64, NB), dim3(256), 0, stream>>>(C, Ct_lh);
  k_prep_q<<<dim3(NLQ / 64, NH / 64, NB), dim3(256), 0, stream>>>(Q, w, Qtw3);
  k_prep_bf16<<<dim3(NB * NH * NLQ / 2048), dim3(256), 0, stream>>>(Q, Qb_hm);
  k_prep_bf16<<<dim3(NH * 4 * NH / 2048), dim3(256), 0, stream>>>(W, Wb);
  k_s1<<<dim3(NB * (NLC / 256)), dim3(256), 0, stream>>>(C, w, s1);
  k_s2<<<dim3(NB), dim3(256), 0, stream>>>(Q, w, s2);
  k_sgemm<<<dim3(NLQ / 128, NLC / 128, NB), dim3(256), 0, stream>>>(
      Ct_lh, Qtw3, s1, s2, S);
  k_rowstats<<<dim3(NB * NLC / 4), dim3(256), 0, stream>>>(S, qmask, rmax,
                                                           rinv);
  k_colpart<<<dim3(NB * 4 * LCHUNK), dim3(256), 0, stream>>>(S, cmask, pmax,
                                                             psum);
  k_colfin<<<dim3(NB * NLQ / 256), dim3(256), 0, stream>>>(pmax, psum, cmax,
                                                           cinv);
  k_tgemm<<<dim3(4, KSPLIT, NB), dim3(256), 0, stream>>>(C, S, cmask, cmax,
                                                         cinv, Tp);
  k_tfin<<<dim3(NB * NH * NLQ / 1024), dim3(256), 0, stream>>>(Tp, Tt);
  k_abgemm<<<dim3(4, NLC / 128, NB), dim3(256), 0, stream>>>(
      S, Qb_hm, Tt, Ct_lh, qmask, rmax, rinv, A_lh, CtBv_lh);
  k_out<<<dim3(NLC / 128, NH / 128, NB), dim3(256), 0, stream>>>(
      Wb, Ct_lh, A_lh, CtBv_lh, br, out);
}

// Round 6
// 176.938 us; speedup vs baseline: 3.7361x; 1.0701x over previous
//
#include <hip/hip_runtime.h>
#include <math.h>

#define NB 32
#define NH 256
#define NLC 1024
#define NLQ 256
#define NEGV (-1e30f)
#define LCHUNK 16  // column-stats l-chunks (each 64 rows)
#define KSPLIT 4   // tgemm split-K factor

typedef short short8 __attribute__((ext_vector_type(8)));
typedef float f32x4 __attribute__((ext_vector_type(4)));

__device__ inline short bf16_of(float f) {
  union { float f; unsigned u; } v;
  v.f = f;
  unsigned r = (v.u + 0x7fffu + ((v.u >> 16) & 1u)) >> 16;
  return (short)r;
}
__device__ inline float f_of(short s) {
  union { unsigned u; float f; } v;
  v.u = ((unsigned)(unsigned short)s) << 16;
  return v.f;
}
__device__ inline short8 cvt8(float4 a, float4 b) {
  short8 o;
  o[0] = bf16_of(a.x); o[1] = bf16_of(a.y); o[2] = bf16_of(a.z); o[3] = bf16_of(a.w);
  o[4] = bf16_of(b.x); o[5] = bf16_of(b.y); o[6] = bf16_of(b.z); o[7] = bf16_of(b.w);
  return o;
}

// ---- swizzled 128x32 bf16 LDS tile helpers (row = 64B, slot ^= (row>>1)&3) ----
__device__ inline void lds_w8(short* lds, int r, int c, short8 v) {
  int byteoff = (r << 6) + (((c ^ ((r >> 1) & 3)) & 3) << 4);
  *(short8*)((char*)lds + byteoff) = v;
}
__device__ inline short8 lds_r8(const short* lds, int R, int g) {
  int byteoff = (R << 6) + (((g ^ ((R >> 1) & 3)) & 3) << 4);
  return *(const short8*)((const char*)lds + byteoff);
}
// global_load_lds staging of a 128x32 bf16 tile from K-minor src (ld elements).
// Source group pre-permuted per-lane so linear LDS bytes match swizzled reads.
__device__ inline void stage_g(const short* src, int ld, short* lds, int t) {
  int L = t & 63, w = t >> 6;
  int cp = (L & 3) ^ ((L >> 3) & 3);
#pragma unroll
  for (int i = 0; i < 2; ++i) {
    int seg = w + i * 4;
    const short* g = src + (size_t)(seg * 16 + (L >> 2)) * ld + cp * 8;
    __builtin_amdgcn_global_load_lds(
        (const __attribute__((address_space(1))) unsigned int*)g,
        (__attribute__((address_space(3))) unsigned int*)(lds + seg * 512), 16,
        0, 0);
  }
}

#define GEMM_IDS                                       \
  int t = threadIdx.x, lane = t & 63, w = t >> 6;      \
  int ln = lane & 15, g = lane >> 4;                   \
  int wr = (w >> 1) << 6, wc = (w & 1) << 6;           \
  (void)wr; (void)wc;

#define MFMA_STEP(AS, BS)                                                      \
  {                                                                            \
    short8 af[4], bfr[4];                                                      \
    _Pragma("unroll") for (int mi = 0; mi < 4; ++mi) af[mi] =                  \
        lds_r8(AS, wr + mi * 16 + ln, g);                                      \
    _Pragma("unroll") for (int ni = 0; ni < 4; ++ni) bfr[ni] =                 \
        lds_r8(BS, wc + ni * 16 + ln, g);                                      \
    _Pragma("unroll") for (int mi = 0; mi < 4; ++mi)                           \
        _Pragma("unroll") for (int ni = 0; ni < 4; ++ni) acc[mi][ni] =         \
            __builtin_amdgcn_mfma_f32_16x16x32_bf16(af[mi], bfr[ni],           \
                                                    acc[mi][ni], 0, 0, 0);     \
  }

// ---------------- prep: Ct_lh[l][h] = bf16(C[h][l]) ----------------
__global__ __launch_bounds__(256) void k_prep_c(const float* __restrict__ C,
                                                short* __restrict__ Ct_lh) {
  __shared__ float Ts[64][65];
  int b = blockIdx.z, h0 = blockIdx.y << 6, l0 = blockIdx.x << 6;
  int t = threadIdx.x;
  int hr = t >> 4, lc = (t & 15) << 2;
  const float* Cb = C + ((size_t)b * NH + h0) * NLC + l0;
#pragma unroll
  for (int i = 0; i < 4; ++i) {
    float4 v = *(const float4*)&Cb[(size_t)(hr + i * 16) * NLC + lc];
    Ts[hr + i * 16][lc + 0] = v.x;
    Ts[hr + i * 16][lc + 1] = v.y;
    Ts[hr + i * 16][lc + 2] = v.z;
    Ts[hr + i * 16][lc + 3] = v.w;
  }
  __syncthreads();
  int lr = t >> 2, hc = (t & 3) << 4;
  short* dst = &Ct_lh[((size_t)b * NLC + l0 + lr) * NH + h0 + hc];
  short8 o0, o1;
#pragma unroll
  for (int j = 0; j < 8; ++j) o0[j] = bf16_of(Ts[hc + j][lr]);
#pragma unroll
  for (int j = 0; j < 8; ++j) o1[j] = bf16_of(Ts[hc + 8 + j][lr]);
  *(short8*)dst = o0;
  *(short8*)(dst + 8) = o1;
}

// ---------------- prep: Qtw3[m][h] = bf16(Q[h][m]*w3[h]) ----------------
__global__ __launch_bounds__(256) void k_prep_q(const float* __restrict__ Q,
                                                const float* __restrict__ w,
                                                short* __restrict__ Qtw3) {
  __shared__ float Ts[64][65];
  int b = blockIdx.z, h0 = blockIdx.y << 6, m0 = blockIdx.x << 6;
  int t = threadIdx.x;
  int hr = t >> 4, mc = (t & 15) << 2;
  const float* w3 = w + 2 * NH;
  const float* Qb = Q + ((size_t)b * NH + h0) * NLQ + m0;
#pragma unroll
  for (int i = 0; i < 4; ++i) {
    int h = hr + i * 16;
    float w3v = w3[h0 + h];
    float4 v = *(const float4*)&Qb[(size_t)h * NLQ + mc];
    Ts[h][mc + 0] = v.x * w3v;
    Ts[h][mc + 1] = v.y * w3v;
    Ts[h][mc + 2] = v.z * w3v;
    Ts[h][mc + 3] = v.w * w3v;
  }
  __syncthreads();
  int mr = t >> 2, hc = (t & 3) << 4;
  short* dst = &Qtw3[((size_t)b * NLQ + m0 + mr) * NH + h0 + hc];
  short8 o0, o1;
#pragma unroll
  for (int j = 0; j < 8; ++j) o0[j] = bf16_of(Ts[hc + j][mr]);
#pragma unroll
  for (int j = 0; j < 8; ++j) o1[j] = bf16_of(Ts[hc + 8 + j][mr]);
  *(short8*)dst = o0;
  *(short8*)(dst + 8) = o1;
}

// ---------------- prep: plain f32 -> bf16 copies ----------------
__global__ __launch_bounds__(256) void k_prep_bf16(const float* __restrict__ X,
                                                   short* __restrict__ Y) {
  size_t i = ((size_t)blockIdx.x * 256 + threadIdx.x) * 8;
  float4 v0 = *(const float4*)&X[i];
  float4 v1 = *(const float4*)&X[i + 4];
  *(short8*)&Y[i] = cvt8(v0, v1);
}

// s1[b][l] = sum_h C[b][h][l] * w1[h]
__global__ __launch_bounds__(256) void k_s1(const float* __restrict__ C,
                                            const float* __restrict__ w,
                                            float* __restrict__ s1) {
  int b = blockIdx.x >> 2;
  int l = ((blockIdx.x & 3) << 8) + threadIdx.x;
  const float* Cb = C + (size_t)b * NH * NLC;
  float acc = 0.f;
#pragma unroll 8
  for (int h = 0; h < NH; ++h) acc += Cb[(size_t)h * NLC + l] * w[h];
  s1[b * NLC + l] = acc;
}

// s2[b][m] = sum_h Q[b][h][m] * w2[h]
__global__ __launch_bounds__(256) void k_s2(const float* __restrict__ Q,
                                            const float* __restrict__ w,
                                            float* __restrict__ s2) {
  int b = blockIdx.x;
  int m = threadIdx.x;
  const float* Qb = Q + (size_t)b * NH * NLQ;
  const float* w2 = w + NH;
  float acc = 0.f;
#pragma unroll 8
  for (int h = 0; h < NH; ++h) acc += Qb[(size_t)h * NLQ + m] * w2[h];
  s2[b * NLQ + m] = acc;
}

// ---------------- S = Ct_lh @ Qtw3^T + s1 + s2  (M=l, N=m, K=h) ----------------
__global__ __launch_bounds__(256) void k_sgemm(
    const short* __restrict__ Ct_lh, const short* __restrict__ Qtw3,
    const float* __restrict__ s1, const float* __restrict__ s2,
    float* __restrict__ S) {
  __shared__ short As[4096], Bs[4096];
  int b = blockIdx.z, l0 = blockIdx.y << 7, m0 = blockIdx.x << 7;
  GEMM_IDS
  const short* Ag = Ct_lh + ((size_t)b * NLC + l0) * NH;
  const short* Bg = Qtw3 + ((size_t)b * NLQ + m0) * NH;
  f32x4 acc[4][4] = {};
  for (int k0 = 0; k0 < NH; k0 += 32) {
    __syncthreads();
    stage_g(Ag + k0, NH, As, t);
    stage_g(Bg + k0, NH, Bs, t);
    __syncthreads();
    MFMA_STEP(As, Bs)
  }
#pragma unroll
  for (int mi = 0; mi < 4; ++mi)
#pragma unroll
    for (int ni = 0; ni < 4; ++ni)
#pragma unroll
      for (int r = 0; r < 4; ++r) {
        int l = l0 + wr + mi * 16 + g * 4 + r;
        int m = m0 + wc + ni * 16 + ln;
        S[((size_t)b * NLC + l) * NLQ + m] =
            acc[mi][ni][r] + s1[b * NLC + l] + s2[b * NLQ + m];
      }
}

// per-column (over l) masked max & sum-exp partials, one 64-row chunk per block.
__global__ __launch_bounds__(256) void k_colpart(const float* __restrict__ S,
                                                 const int* __restrict__ cmask,
                                                 float* __restrict__ pmax,
                                                 float* __restrict__ psum) {
  int idx = blockIdx.x;  // ((b*4 + mb)*LCHUNK + chunk)
  int chunk = idx & (LCHUNK - 1);
  int mb = (idx >> 4) & 3;
  int b = idx >> 6;
  int m0 = mb << 6;
  int tx = threadIdx.x & 63, ty = threadIdx.x >> 6;
  const float* Sb = S + (size_t)b * NLC * NLQ + (size_t)(chunk * 64) * NLQ;
  const int* cm = cmask + b * NLC + chunk * 64;
  float mx = -INFINITY, sm = 0.f;
#pragma unroll 4
  for (int l = ty; l < 64; l += 4) {
    float x = Sb[(size_t)l * NLQ + m0 + tx] + (cm[l] ? 0.f : NEGV);
    float nmx = fmaxf(mx, x);
    sm = sm * expf(mx - nmx) + expf(x - nmx);
    mx = nmx;
  }
  __shared__ float smx[4][64], ssm[4][64];
  smx[ty][tx] = mx;
  ssm[ty][tx] = sm;
  __syncthreads();
  if (ty == 0) {
#pragma unroll
    for (int r = 1; r < 4; ++r) {
      float m2 = smx[r][tx], s2 = ssm[r][tx];
      float nm = fmaxf(mx, m2);
      sm = sm * expf(mx - nm) + s2 * expf(m2 - nm);
      mx = nm;
    }
    int m = (b << 8) + m0 + tx;  // global column id
    pmax[(size_t)m * LCHUNK + chunk] = mx;
    psum[(size_t)m * LCHUNK + chunk] = sm;
  }
}

// combine LCHUNK partials per column -> cmax, cinv. One thread per column.
__global__ __launch_bounds__(256) void k_colfin(const float* __restrict__ pmax,
                                                const float* __restrict__ psum,
                                                float* __restrict__ cmax,
                                                float* __restrict__ cinv) {
  int m = blockIdx.x * 256 + threadIdx.x;  // [0, NB*NLQ)
  const float* pm = pmax + (size_t)m * LCHUNK;
  const float* ps = psum + (size_t)m * LCHUNK;
  float mx = pm[0], sm = ps[0];
#pragma unroll
  for (int c = 1; c < LCHUNK; ++c) {
    float m2 = pm[c], s2 = ps[c];
    float nm = fmaxf(mx, m2);
    sm = sm * expf(mx - nm) + s2 * expf(m2 - nm);
    mx = nm;
  }
  cmax[m] = mx;
  cinv[m] = 1.0f / sm;
}

// ------ Tp[ks][b][h][m] = sum_{l in chunk ks} C[h][l] * S_col[l][m] ------
// split-K partials (f32); M=h, N=m, K=l chunk of 256. Must run while S is f32.
__global__ __launch_bounds__(256) void k_tgemm(
    const float* __restrict__ C, const float* __restrict__ S,
    const int* __restrict__ cmask, const float* __restrict__ cmax,
    const float* __restrict__ cinv, float* __restrict__ Tp) {
  __shared__ short As[4096], Bs[4096];
  int b = blockIdx.z;
  int ks = blockIdx.y;
  int h0 = (blockIdx.x & 1) << 7;
  int m0 = (blockIdx.x >> 1) << 7;
  GEMM_IDS
  const float* Cb = C + ((size_t)b * NH + h0) * NLC;
  const float* Sb = S + (size_t)b * NLC * NLQ;
  const float* cmx = cmax + b * NLQ + m0;
  const float* civ = cinv + b * NLQ + m0;
  const int* cm = cmask + b * NLC;
  f32x4 acc[4][4] = {};
  int kbeg = ks * (NLC / KSPLIT), kend = kbeg + NLC / KSPLIT;
  for (int k0 = kbeg; k0 < kend; k0 += 32) {
    __syncthreads();
    {  // A: reg-convert from f32 C (rows h, K=l minor)
      int c = lane & 3;
#pragma unroll
      for (int i = 0; i < 2; ++i) {
        int seg = w + i * 4, r = seg * 16 + (lane >> 2);
        const float* src = &Cb[(size_t)r * NLC + k0 + c * 8];
        float4 v0 = *(const float4*)src;
        float4 v1 = *(const float4*)(src + 4);
        lds_w8(As, r, c, cvt8(v0, v1));
      }
    }
    {  // B: transposing exp-staging from f32 S (rows m, K=l)
      int lloc = t >> 3, l = k0 + lloc;
      float cmf = (float)cm[l];
      const float* srow = &Sb[(size_t)l * NLQ + m0];
      int g2 = lloc >> 3, kin = lloc & 7;
#pragma unroll
      for (int mi4 = 0; mi4 < 4; ++mi4) {
        int m = ((t & 7) << 2) + (mi4 << 5);
        float4 sv = *(const float4*)&srow[m];
        float p[4];
        p[0] = expf(sv.x - cmx[m + 0]) * civ[m + 0] * cmf;
        p[1] = expf(sv.y - cmx[m + 1]) * civ[m + 1] * cmf;
        p[2] = expf(sv.z - cmx[m + 2]) * civ[m + 2] * cmf;
        p[3] = expf(sv.w - cmx[m + 3]) * civ[m + 3] * cmf;
#pragma unroll
        for (int j = 0; j < 4; ++j) {
          int R = m + j;
          int byteoff =
              (R << 6) + (((g2 ^ ((R >> 1) & 3)) & 3) << 4) + (kin << 1);
          *(short*)((char*)Bs + byteoff) = bf16_of(p[j]);
        }
      }
    }
    __syncthreads();
    MFMA_STEP(As, Bs)
  }
  float* dst = Tp + ((size_t)ks * NB + b) * NH * NLQ;
#pragma unroll
  for (int mi = 0; mi < 4; ++mi)
#pragma unroll
    for (int ni = 0; ni < 4; ++ni)
#pragma unroll
      for (int r = 0; r < 4; ++r) {
        int h = h0 + wr + mi * 16 + g * 4 + r;
        int m = m0 + wc + ni * 16 + ln;
        dst[(size_t)h * NLQ + m] = acc[mi][ni][r];
      }
}

// reduce KSPLIT partials -> bf16 Tt[b][h][m]
__global__ __launch_bounds__(256) void k_tfin(const float* __restrict__ Tp,
                                              short* __restrict__ Tt) {
  size_t i = ((size_t)blockIdx.x * 256 + threadIdx.x) * 4;
  const size_t stride = (size_t)NB * NH * NLQ;
  float4 s = *(const float4*)&Tp[i];
#pragma unroll
  for (int ks = 1; ks < KSPLIT; ++ks) {
    float4 v = *(const float4*)&Tp[i + ks * stride];
    s.x += v.x; s.y += v.y; s.z += v.z; s.w += v.w;
  }
  short4 o;
  o.x = bf16_of(s.x);
  o.y = bf16_of(s.y);
  o.z = bf16_of(s.z);
  o.w = bf16_of(s.w);
  *(short4*)&Tt[i] = o;
}

// ---- row softmax, IN PLACE: writes bf16 P_row into the first 512B of each
// 1KB f32 S row (each wave reads its whole row into regs before storing).
// P_row[l][m] = exp(S+negq-max)*inv, row stride = 512 shorts.
__global__ __launch_bounds__(256) void k_rowsoft(float* __restrict__ S,
                                                 const int* __restrict__ qmask) {
  int wave = threadIdx.x >> 6, lane = threadIdx.x & 63;
  int idx = (blockIdx.x << 2) + wave;  // row id in [0, NB*NLC)
  int b = idx >> 10;
  float* row = S + (size_t)idx * NLQ;
  const int* qm = qmask + b * NLQ;
  int m4 = lane << 2;
  float4 v = *(const float4*)&row[m4];
  int4 q = *(const int4*)&qm[m4];
  float x0 = v.x + (q.x ? 0.f : NEGV);
  float x1 = v.y + (q.y ? 0.f : NEGV);
  float x2 = v.z + (q.z ? 0.f : NEGV);
  float x3 = v.w + (q.w ? 0.f : NEGV);
  float mx = fmaxf(fmaxf(x0, x1), fmaxf(x2, x3));
#pragma unroll
  for (int off = 32; off > 0; off >>= 1) mx = fmaxf(mx, __shfl_xor(mx, off));
  float p0 = expf(x0 - mx), p1 = expf(x1 - mx);
  float p2 = expf(x2 - mx), p3 = expf(x3 - mx);
  float sm = p0 + p1 + p2 + p3;
#pragma unroll
  for (int off = 32; off > 0; off >>= 1) sm += __shfl_xor(sm, off);
  float iv = 1.0f / sm;
  short4 o;
  o.x = bf16_of(p0 * iv);
  o.y = bf16_of(p1 * iv);
  o.z = bf16_of(p2 * iv);
  o.w = bf16_of(p3 * iv);
  *(short4*)((short*)row + m4) = o;
}

// ---- [A | Ct*Bv][l][h] = f(sum_m P_row[l][m] * X[h][m])  (M=l, N=h', K=m) ----
// Pure-DMA staging: A from in-place P_row (ld=512), B from bf16 Qb or Tt.
__global__ __launch_bounds__(256) void k_abgemm(
    const short* __restrict__ Prow, const short* __restrict__ Qb_hm,
    const short* __restrict__ Tt, const short* __restrict__ Ct_lh,
    short* __restrict__ A_lh, short* __restrict__ CtBv_lh) {
  __shared__ short As[4096], Bs[4096];
  int b = blockIdx.z, l0 = blockIdx.y << 7, nb = blockIdx.x;
  GEMM_IDS
  const short* Ag = Prow + ((size_t)b * NLC + l0) * 512;
  const short* Bbase = (nb < 2)
                           ? Qb_hm + ((size_t)b * NH + nb * 128) * NLQ
                           : Tt + ((size_t)b * NH + (nb - 2) * 128) * NLQ;
  f32x4 acc[4][4] = {};
  for (int k0 = 0; k0 < NLQ; k0 += 32) {
    __syncthreads();
    stage_g(Ag + k0, 512, As, t);
    stage_g(Bbase + k0, NLQ, Bs, t);
    __syncthreads();
    MFMA_STEP(As, Bs)
  }
  int hbase = (nb & 1) << 7;
  if (nb < 2) {
#pragma unroll
    for (int mi = 0; mi < 4; ++mi)
#pragma unroll
      for (int ni = 0; ni < 4; ++ni)
#pragma unroll
        for (int r = 0; r < 4; ++r) {
          int l = l0 + wr + mi * 16 + g * 4 + r;
          int h = hbase + wc + ni * 16 + ln;
          A_lh[((size_t)b * NLC + l) * NH + h] = bf16_of(acc[mi][ni][r]);
        }
  } else {
#pragma unroll
    for (int mi = 0; mi < 4; ++mi)
#pragma unroll
      for (int ni = 0; ni < 4; ++ni)
#pragma unroll
        for (int r = 0; r < 4; ++r) {
          int l = l0 + wr + mi * 16 + g * 4 + r;
          int h = hbase + wc + ni * 16 + ln;
          size_t off = ((size_t)b * NLC + l) * NH + h;
          CtBv_lh[off] = bf16_of(f_of(Ct_lh[off]) * acc[mi][ni][r]);
        }
  }
}

// -------- out[h][l] = relu(b + sum_f W[h][f]*cat[l][f])  (M=h, N=l, K=f) ------
// cat regions along f: [Ct | A | Ct*A | Ct*Bv]; Wb is bf16 W_res.
__global__ __launch_bounds__(256) void k_out(
    const short* __restrict__ Wb, const short* __restrict__ Ct_lh,
    const short* __restrict__ A_lh, const short* __restrict__ CtBv_lh,
    const float* __restrict__ br, float* __restrict__ out) {
  __shared__ short As[4096], Bs[4096];
  int b = blockIdx.z, h0 = blockIdx.y << 7, l0 = blockIdx.x << 7;
  GEMM_IDS
  f32x4 acc[4][4] = {};
  for (int k0 = 0; k0 < 4 * NH; k0 += 32) {
    __syncthreads();
    // A: bf16 W via global_load_lds (rows h, K=f minor, ld=4*NH)
    stage_g(Wb + (size_t)h0 * (4 * NH) + k0, 4 * NH, As, t);
    int reg = k0 >> 8, ko = k0 & 255;
    if (reg != 2) {  // B: Ct, A, or CtBv directly via global_load_lds
      const short* base = (reg == 0) ? Ct_lh : (reg == 1) ? A_lh : CtBv_lh;
      stage_g(base + ((size_t)b * NLC + l0) * NH + ko, NH, Bs, t);
    } else {  // B: elementwise Ct * A, reg-staged
      int c = lane & 3;
#pragma unroll
      for (int i = 0; i < 2; ++i) {
        int seg = w + i * 4, r = seg * 16 + (lane >> 2);
        size_t off = ((size_t)b * NLC + l0 + r) * NH + ko + c * 8;
        short8 x1 = *(const short8*)&Ct_lh[off];
        short8 x2 = *(const short8*)&A_lh[off];
        short8 o;
#pragma unroll
        for (int j = 0; j < 8; ++j) o[j] = bf16_of(f_of(x1[j]) * f_of(x2[j]));
        lds_w8(Bs, r, c, o);
      }
    }
    __syncthreads();
    MFMA_STEP(As, Bs)
  }
#pragma unroll
  for (int mi = 0; mi < 4; ++mi)
#pragma unroll
    for (int ni = 0; ni < 4; ++ni) {
      int h = h0 + wr + mi * 16 + g * 4;
      int l = l0 + wc + ni * 16 + ln;
#pragma unroll
      for (int r = 0; r < 4; ++r) {
        float bias = br[h + r];
        out[((size_t)b * NH + h + r) * NLC + l] =
            fmaxf(acc[mi][ni][r] + bias, 0.f);
      }
    }
}

extern "C" void kernel_launch(void* const* d_in, const int* in_sizes, int n_in,
                              void* d_out, int out_size, void* d_ws,
                              size_t ws_size, hipStream_t stream) {
  (void)in_sizes;
  (void)n_in;
  (void)out_size;
  (void)ws_size;
  const float* C = (const float*)d_in[0];
  const float* Q = (const float*)d_in[1];
  const int* cmask = (const int*)d_in[2];
  const int* qmask = (const int*)d_in[3];
  const float* w = (const float*)d_in[4];
  const float* W = (const float*)d_in[5];
  const float* br = (const float*)d_in[6];
  float* out = (float*)d_out;

  char* p = (char*)d_ws;
  float* S = (float*)p;       p += (size_t)NB * NLC * NLQ * 4;   // 33.6 MB
  short* Ct_lh = (short*)p;   p += (size_t)NB * NLC * NH * 2;    // 16.8 MB
  short* A_lh = (short*)p;    p += (size_t)NB * NLC * NH * 2;    // 16.8 MB
  short* CtBv_lh = (short*)p; p += (size_t)NB * NLC * NH * 2;    // 16.8 MB
  short* Tt = (short*)p;      p += (size_t)NB * NH * NLQ * 2;    // 4.2 MB
  short* Qtw3 = (short*)p;    p += (size_t)NB * NLQ * NH * 2;    // 4.2 MB
  short* Qb_hm = (short*)p;   p += (size_t)NB * NH * NLQ * 2;    // 4.2 MB
  short* Wb = (short*)p;      p += (size_t)NH * 4 * NH * 2;      // 0.5 MB
  float* s1 = (float*)p;      p += (size_t)NB * NLC * 4;
  float* s2 = (float*)p;      p += (size_t)NB * NLQ * 4;
  float* cmax = (float*)p;    p += (size_t)NB * NLQ * 4;
  float* cinv = (float*)p;    p += (size_t)NB * NLQ * 4;
  float* pmax = (float*)p;    p += (size_t)NB * NLQ * LCHUNK * 4;
  float* psum = (float*)p;    p += (size_t)NB * NLQ * LCHUNK * 4;
  // tgemm split-K partials: reuse A_lh+CtBv_lh (33.6 MB, dead until abgemm).
  float* Tp = (float*)A_lh;
  // in-place row-softmax result: bf16 P_row lives in S (row stride 512 shorts)
  short* Prow = (short*)S;

  k_prep_c<<<dim3(NLC / 64, NH / 64, NB), dim3(256), 0, stream>>>(C, Ct_lh);
  k_prep_q<<<dim3(NLQ / 64, NH / 64, NB), dim3(256), 0, stream>>>(Q, w, Qtw3);
  k_prep_bf16<<<dim3(NB * NH * NLQ / 2048), dim3(256), 0, stream>>>(Q, Qb_hm);
  k_prep_bf16<<<dim3(NH * 4 * NH / 2048), dim3(256), 0, stream>>>(W, Wb);
  k_s1<<<dim3(NB * (NLC / 256)), dim3(256), 0, stream>>>(C, w, s1);
  k_s2<<<dim3(NB), dim3(256), 0, stream>>>(Q, w, s2);
  k_sgemm<<<dim3(NLQ / 128, NLC / 128, NB), dim3(256), 0, stream>>>(
      Ct_lh, Qtw3, s1, s2, S);
  k_colpart<<<dim3(NB * 4 * LCHUNK), dim3(256), 0, stream>>>(S, cmask, pmax,
                                                             psum);
  k_colfin<<<dim3(NB * NLQ / 256), dim3(256), 0, stream>>>(pmax, psum, cmax,
                                                           cinv);
  // tgemm/tfin read f32 S -> must precede the in-place rowsoft overwrite.
  k_tgemm<<<dim3(4, KSPLIT, NB), dim3(256), 0, stream>>>(C, S, cmask, cmax,
                                                         cinv, Tp);
  k_tfin<<<dim3(NB * NH * NLQ / 1024), dim3(256), 0, stream>>>(Tp, Tt);
  k_rowsoft<<<dim3(NB * NLC / 4), dim3(256), 0, stream>>>(S, qmask);
  k_abgemm<<<dim3(4, NLC / 128, NB), dim3(256), 0, stream>>>(
      Prow, Qb_hm, Tt, Ct_lh, A_lh, CtBv_lh);
  k_out<<<dim3(NLC / 128, NH / 128, NB), dim3(256), 0, stream>>>(
      Wb, Ct_lh, A_lh, CtBv_lh, br, out);
}